// Round 4
// baseline (643.236 us; speedup 1.0000x reference)
//
#include <hip/hip_runtime.h>
#include <cmath>
#include <stdint.h>

#define NPTS   86016
#define NB     (1 << 18)     // histogram bins per level (f32 score bits >> 12)
#define K_TOP  1000
#define NOUT   3000
#define NWORDS 47            // ceil(3000/64)
#define MROW   48            // padded words per mask row
#define CAND_CAP 16384

// ---- workspace layout (bytes) ----
#define HIST_OFF   0
#define CNT_OFF    (NB * 3 * 4)                 // 3,145,728
// cnt[0..2]=sure_cnt  [3..5]=cand_cnt  [6..8]=binB  [9..11]=Rneed
#define MEMSET_BYTES (CNT_OFF + 64)
#define KEYS_OFF   (CNT_OFF + 64)
#define LAB_OFF    (KEYS_OFF + NPTS * 8)
#define SURE_OFF   (LAB_OFF + NPTS * 4)
#define CAND_OFF   (SURE_OFF + 3 * 1024 * 8)
#define SURV_OFF   (CAND_OFF + 3 * CAND_CAP * 8)
#define MASK_OFF   (SURV_OFF + NOUT * 8 + 64)

// stepwise-f32 sigmoid: CR f32 exp, then IEEE f32 add + div (matches numpy per-op chain)
__device__ __forceinline__ float sig_f32_stepwise(float x) {
    float e = (float)exp(-(double)x);   // correctly-rounded f32 exp(-x)
    return 1.0f / (1.0f + e);           // f32 add (CR), f32 div (CR)
}

// ---------------- kernel 1: f32 scores / labels / keys / histogram ----------------
__global__ void score_kernel(const float* __restrict__ cls0, const float* __restrict__ cls1,
                             const float* __restrict__ cls2,
                             const float* __restrict__ ctn0, const float* __restrict__ ctn1,
                             const float* __restrict__ ctn2,
                             unsigned long long* __restrict__ keys,
                             int* __restrict__ labels, int* __restrict__ hist) {
    int g = blockIdx.x * blockDim.x + threadIdx.x;
    if (g >= NPTS) return;
    int lv, p, HW;
    const float *cls, *ctn;
    if (g < 65536)      { lv = 0; p = g;         HW = 65536; cls = cls0; ctn = ctn0; }
    else if (g < 81920) { lv = 1; p = g - 65536; HW = 16384; cls = cls1; ctn = ctn1; }
    else                { lv = 2; p = g - 81920; HW = 4096;  cls = cls2; ctn = ctn2; }

    float sc = sig_f32_stepwise(ctn[p]);
    float best = -1.0f; int lab = 0;
    for (int c = 0; c < 80; c++) {
        float s  = sig_f32_stepwise(cls[c * HW + p]);
        float pr = s * sc;              // f32 mul
        float sj = __fsqrt_rn(pr);      // CR f32 sqrt == np.sqrt
        if (sj > best) { best = sj; lab = c; }  // first-occurrence argmax
    }
    unsigned int bits = __float_as_uint(best);  // score in (0,1]: positive -> bit order == value order
    unsigned long long key = ((unsigned long long)bits << 32) | (0xFFFFFFFFu - (unsigned)g);
    keys[g] = key;
    labels[g] = lab;
    atomicAdd(&hist[lv * NB + (int)(bits >> 12)], 1);
}

// ---------------- kernel 2: per-level cutoff bin via suffix scan ----------------
__global__ void thresh_kernel(const int* __restrict__ hist, int* __restrict__ cnt) {
    int lv = blockIdx.x, tid = threadIdx.x;
    const int* h = hist + lv * NB;
    __shared__ int part[1024];
    __shared__ int s_chunk, s_above;
    __shared__ int bins[257];

    part[tid] = 0;
    __syncthreads();
    for (int i = tid; i < NB; i += 1024) {
        int c = h[i];
        if (c) atomicAdd(&part[i >> 8], c);
    }
    __syncthreads();
    // suffix sums over 1024 chunk-partials
    for (int off = 1; off < 1024; off <<= 1) {
        int v = part[tid] + ((tid + off < 1024) ? part[tid + off] : 0);
        __syncthreads(); part[tid] = v; __syncthreads();
    }
    int nxt = (tid < 1023) ? part[tid + 1] : 0;
    if (part[tid] >= K_TOP && nxt < K_TOP) { s_chunk = tid; s_above = nxt; }
    __syncthreads();
    int chunk = s_chunk, above = s_above;

    if (tid < 256) bins[tid] = h[chunk * 256 + tid];
    __syncthreads();
    for (int off = 1; off < 256; off <<= 1) {
        int v = 0;
        if (tid < 256) v = bins[tid] + ((tid + off < 256) ? bins[tid + off] : 0);
        __syncthreads(); if (tid < 256) bins[tid] = v; __syncthreads();
    }
    if (tid < 256) {
        int ge    = above + bins[tid];
        int genxt = above + ((tid < 255) ? bins[tid + 1] : 0);
        if (ge >= K_TOP && genxt < K_TOP) {
            cnt[6 + lv] = chunk * 256 + tid;  // cutoff bin B
            cnt[9 + lv] = K_TOP - genxt;      // R needed from bin B
        }
    }
}

// ---------------- kernel 3: compact sure / candidate keys ----------------
__global__ void compact_kernel(const unsigned long long* __restrict__ keys,
                               int* __restrict__ cnt,
                               unsigned long long* __restrict__ sure,
                               unsigned long long* __restrict__ cand) {
    int g = blockIdx.x * blockDim.x + threadIdx.x;
    if (g >= NPTS) return;
    int lv = (g < 65536) ? 0 : (g < 81920 ? 1 : 2);
    unsigned long long key = keys[g];
    int bin = (int)(key >> 44);      // == f32 bits >> 12
    int B = cnt[6 + lv];
    if (bin > B) {
        int i = atomicAdd(&cnt[0 + lv], 1);
        sure[lv * 1024 + i] = key;
    } else if (bin == B) {
        int i = atomicAdd(&cnt[3 + lv], 1);
        if (i < CAND_CAP) cand[lv * CAND_CAP + i] = key;
    }
}

// ---------------- kernel 4: per-level candidate sort + build survivor set ----------------
__global__ void select_kernel(const int* __restrict__ cnt,
                              const unsigned long long* __restrict__ sure,
                              unsigned long long* __restrict__ cand,
                              unsigned long long* __restrict__ surv) {
    int lv = blockIdx.x, tid = threadIdx.x;
    unsigned long long* c = cand + lv * CAND_CAP;
    int n = cnt[3 + lv]; if (n > CAND_CAP) n = CAND_CAP;
    int R = cnt[9 + lv];
    int Ca = K_TOP - R;
    int m = 1; while (m < n) m <<= 1;
    for (int t = n + tid; t < m; t += 1024) c[t] = 0ULL;
    __syncthreads();
    for (int k = 2; k <= m; k <<= 1)
        for (int j = k >> 1; j > 0; j >>= 1) {
            for (int t = tid; t < m; t += 1024) {
                int l = t ^ j;
                if (l > t) {
                    unsigned long long a = c[t], b = c[l];
                    // descending sort: key encodes (score bits desc, index asc via 0xFFFFFFFF-g)
                    if (((t & k) == 0) ? (a < b) : (a > b)) { c[t] = b; c[l] = a; }
                }
            }
            __syncthreads();
        }
    for (int t = tid; t < Ca; t += 1024) surv[lv * K_TOP + t] = sure[lv * 1024 + t];
    for (int t = tid; t < R;  t += 1024) surv[lv * K_TOP + Ca + t] = c[t];
}

// ---------------- kernel 5: global sort of 3000 survivors + emit ----------------
__global__ void sort_emit_kernel(const unsigned long long* __restrict__ surv,
                                 const int* __restrict__ labels,
                                 const float* __restrict__ reg0, const float* __restrict__ reg1,
                                 const float* __restrict__ reg2,
                                 const float* __restrict__ scales,
                                 float* __restrict__ out) {
    __shared__ unsigned long long s[4096];
    int tid = threadIdx.x;
    for (int t = tid; t < 4096; t += 1024) s[t] = (t < NOUT) ? surv[t] : 0ULL;
    __syncthreads();
    for (int k = 2; k <= 4096; k <<= 1)
        for (int j = k >> 1; j > 0; j >>= 1) {
            for (int t = tid; t < 4096; t += 1024) {
                int l = t ^ j;
                if (l > t) {
                    unsigned long long a = s[t], b = s[l];
                    if (((t & k) == 0) ? (a < b) : (a > b)) { s[t] = b; s[l] = a; }
                }
            }
            __syncthreads();
        }
    for (int r = tid; r < NOUT; r += 1024) {
        unsigned long long key = s[r];
        unsigned int bits = (unsigned)(key >> 32);
        float score = __uint_as_float(bits);
        unsigned int g = 0xFFFFFFFFu - (unsigned)(key & 0xFFFFFFFFULL);
        int lv, p;
        if (g < 65536u)      { lv = 0; p = (int)g; }
        else if (g < 81920u) { lv = 1; p = (int)g - 65536; }
        else                 { lv = 2; p = (int)g - 81920; }
        const float* rp = (lv == 0) ? reg0 : ((lv == 1) ? reg1 : reg2);
        int HW = (lv == 0) ? 65536 : ((lv == 1) ? 16384 : 4096);
        int W = 256 >> lv;
        float strideF = (float)(8 << lv);
        float scale = scales[lv];
        int x = p & (W - 1);
        int y = p >> (8 - lv);
        // per-op f32 decode (matches numpy f32 chain exactly)
        float r0 = fmaxf(0.0f, rp[0 * HW + p] * scale) * strideF;
        float r1 = fmaxf(0.0f, rp[1 * HW + p] * scale) * strideF;
        float r2 = fmaxf(0.0f, rp[2 * HW + p] * scale) * strideF;
        float r3 = fmaxf(0.0f, rp[3 * HW + p] * scale) * strideF;
        float ax = ((float)x + 0.5f) * strideF;
        float ay = ((float)y + 0.5f) * strideF;
        out[r * 4 + 0] = ax - r0;
        out[r * 4 + 1] = ay - r1;
        out[r * 4 + 2] = ax + r2;
        out[r * 4 + 3] = ay + r3;
        out[12000 + r] = score;
        out[15000 + r] = (float)labels[g];
    }
}

// ---------------- kernel 6: suppression bitmask (per-op f32 IoU) ----------------
__global__ void mask_kernel(const float* __restrict__ out,
                            unsigned long long* __restrict__ mask) {
    int unit = blockIdx.x * 4 + (threadIdx.x >> 6);
    int lane = threadIdx.x & 63;
    if (unit >= NOUT * NWORDS) return;
    int i = unit / NWORDS, w = unit % NWORDS;
    int j = w * 64 + lane;
    float x1i = out[i * 4 + 0], y1i = out[i * 4 + 1];
    float x2i = out[i * 4 + 2], y2i = out[i * 4 + 3];
    bool bit = false;
    if (j < NOUT && j > i) {
        float x1j = out[j * 4 + 0], y1j = out[j * 4 + 1];
        float x2j = out[j * 4 + 2], y2j = out[j * 4 + 3];
        float ai = (x2i - x1i) * (y2i - y1i);
        float aj = (x2j - x1j) * (y2j - y1j);
        float xx1 = fmaxf(x1i, x1j), yy1 = fmaxf(y1i, y1j);
        float xx2 = fminf(x2i, x2j), yy2 = fminf(y2i, y2j);
        float ww = fmaxf(1e-10f, xx2 - xx1);
        float hh = fmaxf(1e-10f, yy2 - yy1);
        float inter = ww * hh;
        float iou = inter / (((ai + aj) - inter) + 1e-14f);   // left-to-right f32, as numpy
        bit = ((double)iou > 0.6);   // f32 value vs python float 0.6
    }
    unsigned long long ball = __ballot(bit);
    if (lane == 0) mask[i * MROW + w] = ball;
}

// ---------------- kernel 7: sequential NMS scan (single wave) + final keep ----------------
__global__ void nms_scan_kernel(const unsigned long long* __restrict__ mask,
                                const float* __restrict__ scores_s,
                                float* __restrict__ keep_out) {
    int lane = threadIdx.x;   // 64 threads, one wave
    unsigned long long mysup = 0ULL;
    unsigned long long buf[8];
#pragma unroll
    for (int u = 0; u < 8; u++)
        buf[u] = (lane < NWORDS) ? mask[u * MROW + lane] : 0ULL;
    for (int base = 0; base < NOUT; base += 8) {
#pragma unroll
        for (int u = 0; u < 8; u++) {
            int i = base + u;
            int w = i >> 6, b = i & 63;
            unsigned long long supw = __shfl(mysup, w, 64);
            if (!((supw >> b) & 1ULL)) mysup |= buf[u];
            int nx = i + 8;
            buf[u] = (nx < NOUT && lane < NWORDS) ? mask[nx * MROW + lane] : 0ULL;
        }
    }
    __shared__ unsigned long long ssup[64];
    ssup[lane] = mysup;
    __syncthreads();
    for (int j = lane; j < NOUT; j += 64) {
        bool sup = (ssup[j >> 6] >> (j & 63)) & 1ULL;
        float scv = scores_s[j];
        keep_out[j] = (!sup && ((double)scv > 0.05)) ? 1.0f : 0.0f;
    }
}

extern "C" void kernel_launch(void* const* d_in, const int* in_sizes, int n_in,
                              void* d_out, int out_size, void* d_ws, size_t ws_size,
                              hipStream_t stream) {
    const float* cls0 = (const float*)d_in[0];
    const float* reg0 = (const float*)d_in[1];
    const float* ctn0 = (const float*)d_in[2];
    const float* cls1 = (const float*)d_in[3];
    const float* reg1 = (const float*)d_in[4];
    const float* ctn1 = (const float*)d_in[5];
    const float* cls2 = (const float*)d_in[6];
    const float* reg2 = (const float*)d_in[7];
    const float* ctn2 = (const float*)d_in[8];
    const float* scales = (const float*)d_in[9];

    char* ws = (char*)d_ws;
    int* hist = (int*)(ws + HIST_OFF);
    int* cnt  = (int*)(ws + CNT_OFF);
    unsigned long long* keys = (unsigned long long*)(ws + KEYS_OFF);
    int* labels = (int*)(ws + LAB_OFF);
    unsigned long long* sure = (unsigned long long*)(ws + SURE_OFF);
    unsigned long long* cand = (unsigned long long*)(ws + CAND_OFF);
    unsigned long long* surv = (unsigned long long*)(ws + SURV_OFF);
    unsigned long long* mask = (unsigned long long*)(ws + MASK_OFF);
    float* out = (float*)d_out;

    hipMemsetAsync(ws, 0, MEMSET_BYTES, stream);

    score_kernel<<<(NPTS + 255) / 256, 256, 0, stream>>>(cls0, cls1, cls2, ctn0, ctn1, ctn2,
                                                         keys, labels, hist);
    thresh_kernel<<<3, 1024, 0, stream>>>(hist, cnt);
    compact_kernel<<<(NPTS + 255) / 256, 256, 0, stream>>>(keys, cnt, sure, cand);
    select_kernel<<<3, 1024, 0, stream>>>(cnt, sure, cand, surv);
    sort_emit_kernel<<<1, 1024, 0, stream>>>(surv, labels, reg0, reg1, reg2, scales, out);
    mask_kernel<<<(NOUT * NWORDS + 3) / 4, 256, 0, stream>>>(out, mask);
    nms_scan_kernel<<<1, 64, 0, stream>>>(mask, out + 12000, out + 18000);
}

// Round 5
// 609.147 us; speedup vs baseline: 1.0560x; 1.0560x over previous
//
#include <hip/hip_runtime.h>
#include <cmath>
#include <stdint.h>

#define NPTS   86016
#define NB     (1 << 14)     // histogram bins per level (f32 score bits >> 18)
#define K_TOP  1000
#define NOUT   3000
#define NWORDS 47            // ceil(3000/64)
#define MROW   48            // padded words per mask row
#define CAND_CAP 16384

// ---- workspace layout (bytes) ----
#define HIST_OFF   0
#define CNT_OFF    (NB * 3 * 4)                 // 196,608
// cnt[0..2]=sure_cnt  [3..5]=cand_cnt  [6..8]=binB  [9..11]=Rneed
#define MEMSET_BYTES (CNT_OFF + 64)
#define KEYS_OFF   (CNT_OFF + 64)
#define LAB_OFF    (KEYS_OFF + NPTS * 8)
#define SURE_OFF   (LAB_OFF + NPTS * 4)
#define CAND_OFF   (SURE_OFF + 3 * 1024 * 8)
#define SURV_OFF   (CAND_OFF + 3 * CAND_CAP * 8)
#define MASK_OFF   (SURV_OFF + NOUT * 8 + 64)

// stepwise-f32 sigmoid: CR f32 exp, then IEEE f32 add + div (matches numpy per-op chain)
__device__ __forceinline__ float sig_f32_stepwise(float x) {
    float e = (float)exp(-(double)x);   // correctly-rounded f32 exp(-x)
    return 1.0f / (1.0f + e);           // f32 add (CR), f32 div (CR)
}

// ---------------- kernel 1: f32 scores / labels / keys / histogram ----------------
__global__ void score_kernel(const float* __restrict__ cls0, const float* __restrict__ cls1,
                             const float* __restrict__ cls2,
                             const float* __restrict__ ctn0, const float* __restrict__ ctn1,
                             const float* __restrict__ ctn2,
                             unsigned long long* __restrict__ keys,
                             int* __restrict__ labels, int* __restrict__ hist) {
    int g = blockIdx.x * blockDim.x + threadIdx.x;
    if (g >= NPTS) return;
    int lv, p, HW;
    const float *cls, *ctn;
    if (g < 65536)      { lv = 0; p = g;         HW = 65536; cls = cls0; ctn = ctn0; }
    else if (g < 81920) { lv = 1; p = g - 65536; HW = 16384; cls = cls1; ctn = ctn1; }
    else                { lv = 2; p = g - 81920; HW = 4096;  cls = cls2; ctn = ctn2; }

    float sc = sig_f32_stepwise(ctn[p]);
    float best = -1.0f; int lab = 0;
    for (int c = 0; c < 80; c++) {
        float s  = sig_f32_stepwise(cls[c * HW + p]);
        float pr = s * sc;              // f32 mul
        float sj = __fsqrt_rn(pr);      // CR f32 sqrt == np.sqrt
        if (sj > best) { best = sj; lab = c; }  // first-occurrence argmax
    }
    unsigned int bits = __float_as_uint(best);  // score in (0,1]: positive -> bit order == value order
    unsigned long long key = ((unsigned long long)bits << 32) | (0xFFFFFFFFu - (unsigned)g);
    keys[g] = key;
    labels[g] = lab;
    atomicAdd(&hist[lv * NB + (int)(bits >> 18)], 1);
}

// ---------------- kernel 2: per-level cutoff bin via suffix scan ----------------
__global__ void thresh_kernel(const int* __restrict__ hist, int* __restrict__ cnt) {
    int lv = blockIdx.x, tid = threadIdx.x;
    const int* h = hist + lv * NB;
    __shared__ int part[1024];
    __shared__ int s_chunk, s_above;
    __shared__ int bins[17];

    int sum = 0;
    for (int k = 0; k < 16; k++) sum += h[tid * 16 + k];
    part[tid] = sum;
    __syncthreads();
    // suffix sums over 1024 chunk-partials
    for (int off = 1; off < 1024; off <<= 1) {
        int v = part[tid] + ((tid + off < 1024) ? part[tid + off] : 0);
        __syncthreads(); part[tid] = v; __syncthreads();
    }
    int nxt = (tid < 1023) ? part[tid + 1] : 0;
    if (part[tid] >= K_TOP && nxt < K_TOP) { s_chunk = tid; s_above = nxt; }
    __syncthreads();
    int chunk = s_chunk, above = s_above;

    if (tid < 16) bins[tid] = h[chunk * 16 + tid];
    __syncthreads();
    for (int off = 1; off < 16; off <<= 1) {
        int v = 0;
        if (tid < 16) v = bins[tid] + ((tid + off < 16) ? bins[tid + off] : 0);
        __syncthreads(); if (tid < 16) bins[tid] = v; __syncthreads();
    }
    if (tid < 16) {
        int ge    = above + bins[tid];
        int genxt = above + ((tid < 15) ? bins[tid + 1] : 0);
        if (ge >= K_TOP && genxt < K_TOP) {
            cnt[6 + lv] = chunk * 16 + tid;   // cutoff bin B
            cnt[9 + lv] = K_TOP - genxt;      // R needed from bin B
        }
    }
}

// ---------------- kernel 3: compact sure / candidate keys ----------------
__global__ void compact_kernel(const unsigned long long* __restrict__ keys,
                               int* __restrict__ cnt,
                               unsigned long long* __restrict__ sure,
                               unsigned long long* __restrict__ cand) {
    int g = blockIdx.x * blockDim.x + threadIdx.x;
    if (g >= NPTS) return;
    int lv = (g < 65536) ? 0 : (g < 81920 ? 1 : 2);
    unsigned long long key = keys[g];
    int bin = (int)(key >> 50);      // == f32 bits >> 18
    int B = cnt[6 + lv];
    if (bin > B) {
        int i = atomicAdd(&cnt[0 + lv], 1);
        sure[lv * 1024 + i] = key;
    } else if (bin == B) {
        int i = atomicAdd(&cnt[3 + lv], 1);
        if (i < CAND_CAP) cand[lv * CAND_CAP + i] = key;
    }
}

// ---------------- kernel 4: per-level candidate sort + build survivor set ----------------
__global__ void select_kernel(const int* __restrict__ cnt,
                              const unsigned long long* __restrict__ sure,
                              unsigned long long* __restrict__ cand,
                              unsigned long long* __restrict__ surv) {
    int lv = blockIdx.x, tid = threadIdx.x;
    unsigned long long* c = cand + lv * CAND_CAP;
    int n = cnt[3 + lv]; if (n > CAND_CAP) n = CAND_CAP;
    int R = cnt[9 + lv];
    int Ca = K_TOP - R;
    int m = 1; while (m < n) m <<= 1;
    for (int t = n + tid; t < m; t += 1024) c[t] = 0ULL;
    __syncthreads();
    for (int k = 2; k <= m; k <<= 1)
        for (int j = k >> 1; j > 0; j >>= 1) {
            for (int t = tid; t < m; t += 1024) {
                int l = t ^ j;
                if (l > t) {
                    unsigned long long a = c[t], b = c[l];
                    // descending sort: key encodes (score bits desc, index asc via 0xFFFFFFFF-g)
                    if (((t & k) == 0) ? (a < b) : (a > b)) { c[t] = b; c[l] = a; }
                }
            }
            __syncthreads();
        }
    for (int t = tid; t < Ca; t += 1024) surv[lv * K_TOP + t] = sure[lv * 1024 + t];
    for (int t = tid; t < R;  t += 1024) surv[lv * K_TOP + Ca + t] = c[t];
}

// ---------------- kernel 5: global sort of 3000 survivors + emit ----------------
__global__ void sort_emit_kernel(const unsigned long long* __restrict__ surv,
                                 const int* __restrict__ labels,
                                 const float* __restrict__ reg0, const float* __restrict__ reg1,
                                 const float* __restrict__ reg2,
                                 const float* __restrict__ scales,
                                 float* __restrict__ out) {
    __shared__ unsigned long long s[4096];
    int tid = threadIdx.x;
    for (int t = tid; t < 4096; t += 1024) s[t] = (t < NOUT) ? surv[t] : 0ULL;
    __syncthreads();
    for (int k = 2; k <= 4096; k <<= 1)
        for (int j = k >> 1; j > 0; j >>= 1) {
            for (int t = tid; t < 4096; t += 1024) {
                int l = t ^ j;
                if (l > t) {
                    unsigned long long a = s[t], b = s[l];
                    if (((t & k) == 0) ? (a < b) : (a > b)) { s[t] = b; s[l] = a; }
                }
            }
            __syncthreads();
        }
    for (int r = tid; r < NOUT; r += 1024) {
        unsigned long long key = s[r];
        unsigned int bits = (unsigned)(key >> 32);
        float score = __uint_as_float(bits);
        unsigned int g = 0xFFFFFFFFu - (unsigned)(key & 0xFFFFFFFFULL);
        int lv, p;
        if (g < 65536u)      { lv = 0; p = (int)g; }
        else if (g < 81920u) { lv = 1; p = (int)g - 65536; }
        else                 { lv = 2; p = (int)g - 81920; }
        const float* rp = (lv == 0) ? reg0 : ((lv == 1) ? reg1 : reg2);
        int HW = (lv == 0) ? 65536 : ((lv == 1) ? 16384 : 4096);
        int W = 256 >> lv;
        float strideF = (float)(8 << lv);
        float scale = scales[lv];
        int x = p & (W - 1);
        int y = p >> (8 - lv);
        // per-op f32 decode (matches numpy f32 chain exactly)
        float r0 = fmaxf(0.0f, rp[0 * HW + p] * scale) * strideF;
        float r1 = fmaxf(0.0f, rp[1 * HW + p] * scale) * strideF;
        float r2 = fmaxf(0.0f, rp[2 * HW + p] * scale) * strideF;
        float r3 = fmaxf(0.0f, rp[3 * HW + p] * scale) * strideF;
        float ax = ((float)x + 0.5f) * strideF;
        float ay = ((float)y + 0.5f) * strideF;
        out[r * 4 + 0] = ax - r0;
        out[r * 4 + 1] = ay - r1;
        out[r * 4 + 2] = ax + r2;
        out[r * 4 + 3] = ay + r3;
        out[12000 + r] = score;
        out[15000 + r] = (float)labels[g];
    }
}

// ---------------- kernel 6: suppression bitmask (per-op f32 IoU) ----------------
// only words w >= i>>6 are ever read by the tile scan; skip the rest
__global__ void mask_kernel(const float* __restrict__ out,
                            unsigned long long* __restrict__ mask) {
    int unit = blockIdx.x * 4 + (threadIdx.x >> 6);
    int lane = threadIdx.x & 63;
    if (unit >= NOUT * NWORDS) return;
    int i = unit / NWORDS, w = unit % NWORDS;
    if (w < (i >> 6)) return;       // lower-triangle words never read
    int j = w * 64 + lane;
    float x1i = out[i * 4 + 0], y1i = out[i * 4 + 1];
    float x2i = out[i * 4 + 2], y2i = out[i * 4 + 3];
    bool bit = false;
    if (j < NOUT && j > i) {
        float x1j = out[j * 4 + 0], y1j = out[j * 4 + 1];
        float x2j = out[j * 4 + 2], y2j = out[j * 4 + 3];
        float ai = (x2i - x1i) * (y2i - y1i);
        float aj = (x2j - x1j) * (y2j - y1j);
        float xx1 = fmaxf(x1i, x1j), yy1 = fmaxf(y1i, y1j);
        float xx2 = fminf(x2i, x2j), yy2 = fminf(y2i, y2j);
        float ww = fmaxf(1e-10f, xx2 - xx1);
        float hh = fmaxf(1e-10f, yy2 - yy1);
        float inter = ww * hh;
        float iou = inter / (((ai + aj) - inter) + 1e-14f);   // left-to-right f32, as numpy
        bit = ((double)iou > 0.6);   // f32 value vs python float 0.6
    }
    unsigned long long ball = __ballot(bit);
    if (lane == 0) mask[i * MROW + w] = ball;
}

// ---------------- kernel 7: tiled sequential NMS (single block, 16 waves) ----------------
// Exact refactoring of the serial scan: process 64-row tiles; wave0 runs the
// in-tile serial dependency via shfl; 47 lanes then OR kept rows' later words
// into the LDS suppression state. Tile t+1 is register-prefetched during tile t.
__global__ __launch_bounds__(1024) void nms_tile_kernel(
        const unsigned long long* __restrict__ mask,
        const float* __restrict__ scores_s,
        float* __restrict__ keep_out) {
    __shared__ unsigned long long tile[64 * MROW];   // 24 KB
    __shared__ unsigned long long sup[MROW];
    __shared__ unsigned long long keptMask;
    int tid = threadIdx.x;
    int wave = tid >> 6, lane = tid & 63;
    if (tid < MROW) sup[tid] = 0ULL;

    // prefetch tile 0: wave handles 4 rows; lane covers word T+lane (T=0)
    unsigned long long pre[4];
#pragma unroll
    for (int q = 0; q < 4; q++) {
        int r = wave * 4 + q;     // global row (tile 0)
        pre[q] = (lane < MROW) ? mask[(unsigned)r * MROW + lane] : 0ULL;
    }

    for (int T = 0; T < NWORDS; T++) {
        __syncthreads();   // previous step B done reading tile buffer
#pragma unroll
        for (int q = 0; q < 4; q++) {
            int r = wave * 4 + q;        // row within tile
            int w = T + lane;
            if (w < MROW) tile[r * MROW + w] = pre[q];
        }
        int Tn = T + 1;
        if (Tn < NWORDS) {
#pragma unroll
            for (int q = 0; q < 4; q++) {
                int r = Tn * 64 + wave * 4 + q;   // global row of next tile
                int w = Tn + lane;
                pre[q] = (w < MROW && r < NOUT) ? mask[(unsigned)r * MROW + w] : 0ULL;
            }
        }
        __syncthreads();   // tile stores visible
        if (wave == 0) {
            // step A: serial in-tile scan (rows r0..r0+63)
            unsigned long long myrow = tile[lane * MROW + T];
            unsigned long long cur = sup[T];
            for (int i = 0; i < 64; i++) {
                unsigned long long rowmask = __shfl(myrow, i, 64);
                if (!((cur >> i) & 1ULL)) cur |= rowmask;
            }
            if (lane == 0) { sup[T] = cur; keptMask = ~cur; }
        }
        __syncthreads();
        // step B: lane w ORs kept rows' word w (w > T) into sup[w]
        if (tid < NWORDS && tid > T) {
            int w = tid;
            unsigned long long acc = 0ULL;
            unsigned long long km = keptMask;   // wave-uniform -> uniform branches
            for (int i = 0; i < 64; i++)
                if ((km >> i) & 1ULL) acc |= tile[i * MROW + w];
            sup[w] |= acc;
        }
    }
    __syncthreads();
    for (int j = tid; j < NOUT; j += 1024) {
        bool s = (sup[j >> 6] >> (j & 63)) & 1ULL;
        float scv = scores_s[j];
        keep_out[j] = (!s && ((double)scv > 0.05)) ? 1.0f : 0.0f;
    }
}

extern "C" void kernel_launch(void* const* d_in, const int* in_sizes, int n_in,
                              void* d_out, int out_size, void* d_ws, size_t ws_size,
                              hipStream_t stream) {
    const float* cls0 = (const float*)d_in[0];
    const float* reg0 = (const float*)d_in[1];
    const float* ctn0 = (const float*)d_in[2];
    const float* cls1 = (const float*)d_in[3];
    const float* reg1 = (const float*)d_in[4];
    const float* ctn1 = (const float*)d_in[5];
    const float* cls2 = (const float*)d_in[6];
    const float* reg2 = (const float*)d_in[7];
    const float* ctn2 = (const float*)d_in[8];
    const float* scales = (const float*)d_in[9];

    char* ws = (char*)d_ws;
    int* hist = (int*)(ws + HIST_OFF);
    int* cnt  = (int*)(ws + CNT_OFF);
    unsigned long long* keys = (unsigned long long*)(ws + KEYS_OFF);
    int* labels = (int*)(ws + LAB_OFF);
    unsigned long long* sure = (unsigned long long*)(ws + SURE_OFF);
    unsigned long long* cand = (unsigned long long*)(ws + CAND_OFF);
    unsigned long long* surv = (unsigned long long*)(ws + SURV_OFF);
    unsigned long long* mask = (unsigned long long*)(ws + MASK_OFF);
    float* out = (float*)d_out;

    hipMemsetAsync(ws, 0, MEMSET_BYTES, stream);

    score_kernel<<<(NPTS + 255) / 256, 256, 0, stream>>>(cls0, cls1, cls2, ctn0, ctn1, ctn2,
                                                         keys, labels, hist);
    thresh_kernel<<<3, 1024, 0, stream>>>(hist, cnt);
    compact_kernel<<<(NPTS + 255) / 256, 256, 0, stream>>>(keys, cnt, sure, cand);
    select_kernel<<<3, 1024, 0, stream>>>(cnt, sure, cand, surv);
    sort_emit_kernel<<<1, 1024, 0, stream>>>(surv, labels, reg0, reg1, reg2, scales, out);
    mask_kernel<<<(NOUT * NWORDS + 3) / 4, 256, 0, stream>>>(out, mask);
    nms_tile_kernel<<<1, 1024, 0, stream>>>(mask, out + 12000, out + 18000);
}

// Round 6
// 565.076 us; speedup vs baseline: 1.1383x; 1.0780x over previous
//
#include <hip/hip_runtime.h>
#include <cmath>
#include <stdint.h>

#define NPTS   86016
#define NB     (1 << 14)     // histogram bins per level (f32 score bits >> 18)
#define K_TOP  1000
#define NOUT   3000
#define NWORDS 47            // ceil(3000/64)
#define MROW   48            // padded words per mask row
#define CAND_CAP 16384
#define NTILE  47            // ceil(3000/64)

// ---- workspace layout (bytes) ----
#define HIST_OFF   0
#define CNT_OFF    (NB * 3 * 4)                 // 196,608
// cnt[0..2]=sure_cnt  [3..5]=cand_cnt  [6..8]=binB  [9..11]=Rneed
#define MEMSET_BYTES (CNT_OFF + 64)
#define KEYS_OFF   (CNT_OFF + 64)
#define LAB_OFF    (KEYS_OFF + NPTS * 8)
#define SURE_OFF   (LAB_OFF + NPTS * 4)
#define CAND_OFF   (SURE_OFF + 3 * 1024 * 8)
#define SURV_OFF   (CAND_OFF + 3 * CAND_CAP * 8)
#define MASK_OFF   (SURV_OFF + NOUT * 8 + 64)
#define DIAG_OFF   (MASK_OFF + NOUT * MROW * 8 + 64)   // NTILE*64*8

// stepwise-f32 sigmoid: CR f32 exp, then IEEE f32 add + div (matches numpy per-op chain)
__device__ __forceinline__ float sig_f32_stepwise(float x) {
    float e = (float)exp(-(double)x);   // correctly-rounded f32 exp(-x)
    return 1.0f / (1.0f + e);           // f32 add (CR), f32 div (CR)
}

// ---------------- kernel 1: f32 scores / labels / keys / histogram ----------------
__global__ void score_kernel(const float* __restrict__ cls0, const float* __restrict__ cls1,
                             const float* __restrict__ cls2,
                             const float* __restrict__ ctn0, const float* __restrict__ ctn1,
                             const float* __restrict__ ctn2,
                             unsigned long long* __restrict__ keys,
                             int* __restrict__ labels, int* __restrict__ hist) {
    int g = blockIdx.x * blockDim.x + threadIdx.x;
    if (g >= NPTS) return;
    int lv, p, HW;
    const float *cls, *ctn;
    if (g < 65536)      { lv = 0; p = g;         HW = 65536; cls = cls0; ctn = ctn0; }
    else if (g < 81920) { lv = 1; p = g - 65536; HW = 16384; cls = cls1; ctn = ctn1; }
    else                { lv = 2; p = g - 81920; HW = 4096;  cls = cls2; ctn = ctn2; }

    float sc = sig_f32_stepwise(ctn[p]);
    float best = -1.0f; int lab = 0;
    for (int c = 0; c < 80; c++) {
        float s  = sig_f32_stepwise(cls[c * HW + p]);
        float pr = s * sc;              // f32 mul
        float sj = __fsqrt_rn(pr);      // CR f32 sqrt == np.sqrt
        if (sj > best) { best = sj; lab = c; }  // first-occurrence argmax
    }
    unsigned int bits = __float_as_uint(best);  // score in (0,1]: positive -> bit order == value order
    unsigned long long key = ((unsigned long long)bits << 32) | (0xFFFFFFFFu - (unsigned)g);
    keys[g] = key;
    labels[g] = lab;
    atomicAdd(&hist[lv * NB + (int)(bits >> 18)], 1);
}

// ---------------- kernel 2: per-level cutoff bin via suffix scan ----------------
__global__ void thresh_kernel(const int* __restrict__ hist, int* __restrict__ cnt) {
    int lv = blockIdx.x, tid = threadIdx.x;
    const int* h = hist + lv * NB;
    __shared__ int part[1024];
    __shared__ int s_chunk, s_above;
    __shared__ int bins[17];

    int sum = 0;
    for (int k = 0; k < 16; k++) sum += h[tid * 16 + k];
    part[tid] = sum;
    __syncthreads();
    // suffix sums over 1024 chunk-partials
    for (int off = 1; off < 1024; off <<= 1) {
        int v = part[tid] + ((tid + off < 1024) ? part[tid + off] : 0);
        __syncthreads(); part[tid] = v; __syncthreads();
    }
    int nxt = (tid < 1023) ? part[tid + 1] : 0;
    if (part[tid] >= K_TOP && nxt < K_TOP) { s_chunk = tid; s_above = nxt; }
    __syncthreads();
    int chunk = s_chunk, above = s_above;

    if (tid < 16) bins[tid] = h[chunk * 16 + tid];
    __syncthreads();
    for (int off = 1; off < 16; off <<= 1) {
        int v = 0;
        if (tid < 16) v = bins[tid] + ((tid + off < 16) ? bins[tid + off] : 0);
        __syncthreads(); if (tid < 16) bins[tid] = v; __syncthreads();
    }
    if (tid < 16) {
        int ge    = above + bins[tid];
        int genxt = above + ((tid < 15) ? bins[tid + 1] : 0);
        if (ge >= K_TOP && genxt < K_TOP) {
            cnt[6 + lv] = chunk * 16 + tid;   // cutoff bin B
            cnt[9 + lv] = K_TOP - genxt;      // R needed from bin B
        }
    }
}

// ---------------- kernel 3: compact sure / candidate keys ----------------
__global__ void compact_kernel(const unsigned long long* __restrict__ keys,
                               int* __restrict__ cnt,
                               unsigned long long* __restrict__ sure,
                               unsigned long long* __restrict__ cand) {
    int g = blockIdx.x * blockDim.x + threadIdx.x;
    if (g >= NPTS) return;
    int lv = (g < 65536) ? 0 : (g < 81920 ? 1 : 2);
    unsigned long long key = keys[g];
    int bin = (int)(key >> 50);      // == f32 bits >> 18
    int B = cnt[6 + lv];
    if (bin > B) {
        int i = atomicAdd(&cnt[0 + lv], 1);
        sure[lv * 1024 + i] = key;
    } else if (bin == B) {
        int i = atomicAdd(&cnt[3 + lv], 1);
        if (i < CAND_CAP) cand[lv * CAND_CAP + i] = key;
    }
}

// ---------------- kernel 4: per-level candidate sort + build survivor set ----------------
__global__ void select_kernel(const int* __restrict__ cnt,
                              const unsigned long long* __restrict__ sure,
                              unsigned long long* __restrict__ cand,
                              unsigned long long* __restrict__ surv) {
    int lv = blockIdx.x, tid = threadIdx.x;
    unsigned long long* c = cand + lv * CAND_CAP;
    int n = cnt[3 + lv]; if (n > CAND_CAP) n = CAND_CAP;
    int R = cnt[9 + lv];
    int Ca = K_TOP - R;
    int m = 1; while (m < n) m <<= 1;
    for (int t = n + tid; t < m; t += 1024) c[t] = 0ULL;
    __syncthreads();
    for (int k = 2; k <= m; k <<= 1)
        for (int j = k >> 1; j > 0; j >>= 1) {
            for (int t = tid; t < m; t += 1024) {
                int l = t ^ j;
                if (l > t) {
                    unsigned long long a = c[t], b = c[l];
                    // descending sort: key encodes (score bits desc, index asc via 0xFFFFFFFF-g)
                    if (((t & k) == 0) ? (a < b) : (a > b)) { c[t] = b; c[l] = a; }
                }
            }
            __syncthreads();
        }
    for (int t = tid; t < Ca; t += 1024) surv[lv * K_TOP + t] = sure[lv * 1024 + t];
    for (int t = tid; t < R;  t += 1024) surv[lv * K_TOP + Ca + t] = c[t];
}

// ---------------- kernel 5: global sort of 3000 survivors + emit ----------------
__global__ void sort_emit_kernel(const unsigned long long* __restrict__ surv,
                                 const int* __restrict__ labels,
                                 const float* __restrict__ reg0, const float* __restrict__ reg1,
                                 const float* __restrict__ reg2,
                                 const float* __restrict__ scales,
                                 float* __restrict__ out) {
    __shared__ unsigned long long s[4096];
    int tid = threadIdx.x;
    for (int t = tid; t < 4096; t += 1024) s[t] = (t < NOUT) ? surv[t] : 0ULL;
    __syncthreads();
    for (int k = 2; k <= 4096; k <<= 1)
        for (int j = k >> 1; j > 0; j >>= 1) {
            for (int t = tid; t < 4096; t += 1024) {
                int l = t ^ j;
                if (l > t) {
                    unsigned long long a = s[t], b = s[l];
                    if (((t & k) == 0) ? (a < b) : (a > b)) { s[t] = b; s[l] = a; }
                }
            }
            __syncthreads();
        }
    for (int r = tid; r < NOUT; r += 1024) {
        unsigned long long key = s[r];
        unsigned int bits = (unsigned)(key >> 32);
        float score = __uint_as_float(bits);
        unsigned int g = 0xFFFFFFFFu - (unsigned)(key & 0xFFFFFFFFULL);
        int lv, p;
        if (g < 65536u)      { lv = 0; p = (int)g; }
        else if (g < 81920u) { lv = 1; p = (int)g - 65536; }
        else                 { lv = 2; p = (int)g - 81920; }
        const float* rp = (lv == 0) ? reg0 : ((lv == 1) ? reg1 : reg2);
        int HW = (lv == 0) ? 65536 : ((lv == 1) ? 16384 : 4096);
        int W = 256 >> lv;
        float strideF = (float)(8 << lv);
        float scale = scales[lv];
        int x = p & (W - 1);
        int y = p >> (8 - lv);
        // per-op f32 decode (matches numpy f32 chain exactly)
        float r0 = fmaxf(0.0f, rp[0 * HW + p] * scale) * strideF;
        float r1 = fmaxf(0.0f, rp[1 * HW + p] * scale) * strideF;
        float r2 = fmaxf(0.0f, rp[2 * HW + p] * scale) * strideF;
        float r3 = fmaxf(0.0f, rp[3 * HW + p] * scale) * strideF;
        float ax = ((float)x + 0.5f) * strideF;
        float ay = ((float)y + 0.5f) * strideF;
        out[r * 4 + 0] = ax - r0;
        out[r * 4 + 1] = ay - r1;
        out[r * 4 + 2] = ax + r2;
        out[r * 4 + 3] = ay + r3;
        out[12000 + r] = score;
        out[15000 + r] = (float)labels[g];
    }
}

// ---------------- kernel 6: suppression bitmask (per-op f32 IoU) ----------------
// tile scan reads only words w > i>>6 from mask[] (diagonal word comes from diagT)
__global__ void mask_kernel(const float* __restrict__ out,
                            unsigned long long* __restrict__ mask) {
    int unit = blockIdx.x * 4 + (threadIdx.x >> 6);
    int lane = threadIdx.x & 63;
    if (unit >= NOUT * NWORDS) return;
    int i = unit / NWORDS, w = unit % NWORDS;
    if (w <= (i >> 6)) return;      // diagonal + lower-triangle words never read
    int j = w * 64 + lane;
    float x1i = out[i * 4 + 0], y1i = out[i * 4 + 1];
    float x2i = out[i * 4 + 2], y2i = out[i * 4 + 3];
    bool bit = false;
    if (j < NOUT && j > i) {
        float x1j = out[j * 4 + 0], y1j = out[j * 4 + 1];
        float x2j = out[j * 4 + 2], y2j = out[j * 4 + 3];
        float ai = (x2i - x1i) * (y2i - y1i);
        float aj = (x2j - x1j) * (y2j - y1j);
        float xx1 = fmaxf(x1i, x1j), yy1 = fmaxf(y1i, y1j);
        float xx2 = fminf(x2i, x2j), yy2 = fminf(y2i, y2j);
        float ww = fmaxf(1e-10f, xx2 - xx1);
        float hh = fmaxf(1e-10f, yy2 - yy1);
        float inter = ww * hh;
        float iou = inter / (((ai + aj) - inter) + 1e-14f);   // left-to-right f32, as numpy
        bit = ((double)iou > 0.6);   // f32 value vs python float 0.6
    }
    unsigned long long ball = __ballot(bit);
    if (lane == 0) mask[i * MROW + w] = ball;
}

// ---------------- kernel 6b: transposed diagonal blocks ----------------
// diagT[t*64 + j]: bit i = (row t*64+i suppresses col t*64+j), same f32 IoU chain
__global__ void diag_kernel(const float* __restrict__ out,
                            unsigned long long* __restrict__ diagT) {
    int t = blockIdx.x, j = threadIdx.x;   // 64 threads
    int gj = t * 64 + j;
    __shared__ float bx[64][4];
    if (gj < NOUT) {
        bx[j][0] = out[gj * 4 + 0]; bx[j][1] = out[gj * 4 + 1];
        bx[j][2] = out[gj * 4 + 2]; bx[j][3] = out[gj * 4 + 3];
    } else {
        bx[j][0] = bx[j][1] = bx[j][2] = bx[j][3] = 0.0f;
    }
    __syncthreads();
    unsigned long long col = 0ULL;
    if (gj < NOUT) {
        float x1j = bx[j][0], y1j = bx[j][1], x2j = bx[j][2], y2j = bx[j][3];
        float aj = (x2j - x1j) * (y2j - y1j);
        for (int i = 0; i < j; i++) {          // only i < j suppresses (gi < gj, same tile)
            float x1i = bx[i][0], y1i = bx[i][1], x2i = bx[i][2], y2i = bx[i][3];
            float ai = (x2i - x1i) * (y2i - y1i);
            float xx1 = fmaxf(x1i, x1j), yy1 = fmaxf(y1i, y1j);
            float xx2 = fminf(x2i, x2j), yy2 = fminf(y2i, y2j);
            float ww = fmaxf(1e-10f, xx2 - xx1);
            float hh = fmaxf(1e-10f, yy2 - yy1);
            float inter = ww * hh;
            float iou = inter / (((ai + aj) - inter) + 1e-14f);
            if ((double)iou > 0.6) col |= (1ULL << i);
        }
    }
    diagT[t * 64 + j] = col;
}

// ---------------- kernel 7: tiled sequential NMS (single block, 16 waves) ----------------
// Serial chain is pure ALU: wave0 lane j holds its column word (diagT) in a register
// and runs a 64-step ballot recurrence. Cross-tile words live in registers across all
// 16 waves (4 rows x 1 word each), prefetched a tile ahead, OR-merged via LDS atomics.
__global__ __launch_bounds__(1024) void nms_kernel(
        const unsigned long long* __restrict__ mask,
        const unsigned long long* __restrict__ diagT,
        const float* __restrict__ scores_s,
        float* __restrict__ keep_out) {
    __shared__ unsigned long long sup[MROW];
    __shared__ unsigned long long keptW;
    int tid = threadIdx.x, wave = tid >> 6, lane = tid & 63;
    if (tid < MROW) sup[tid] = 0ULL;

    // prefetch tile 0: wave's 4 rows, word index w = 1 + lane
    unsigned long long reg[4];
    unsigned long long dreg = 0ULL;
#pragma unroll
    for (int q = 0; q < 4; q++) {
        int r = wave * 4 + q;
        int w = 1 + lane;
        reg[q] = (w < NWORDS) ? mask[(unsigned)r * MROW + w] : 0ULL;
    }
    if (wave == 0) dreg = diagT[lane];
    __syncthreads();

    for (int T = 0; T < NWORDS; T++) {
        // ---- step A (wave0): in-tile serial scan, pure ALU ----
        if (wave == 0) {
            unsigned long long col = dreg;
            bool supj = (sup[T] >> lane) & 1ULL;
            for (int i = 0; i < 64; i++) {
                unsigned long long km = __ballot(!supj);
                if (((km >> i) & 1ULL) && ((col >> i) & 1ULL)) supj = true;
            }
            unsigned long long fin = __ballot(!supj);
            if (lane == 0) { keptW = fin; sup[T] = ~fin; }
        }
        __syncthreads();
        // ---- step B (all waves): apply kept rows' later words from registers ----
        unsigned long long km = keptW;
        unsigned long long acc = 0ULL;
#pragma unroll
        for (int q = 0; q < 4; q++)
            if ((km >> (wave * 4 + q)) & 1ULL) acc |= reg[q];
        int w = T + 1 + lane;
        if (w < NWORDS && acc) {
            unsigned lo = (unsigned)acc, hi = (unsigned)(acc >> 32);
            unsigned* s32 = (unsigned*)&sup[w];
            if (lo) atomicOr(&s32[0], lo);
            if (hi) atomicOr(&s32[1], hi);
        }
        // ---- prefetch tile T+1 ----
        int Tn = T + 1;
        if (Tn < NWORDS) {
#pragma unroll
            for (int q = 0; q < 4; q++) {
                int r = Tn * 64 + wave * 4 + q;
                int ww = Tn + 1 + lane;
                reg[q] = (ww < NWORDS && r < NOUT) ? mask[(unsigned)r * MROW + ww] : 0ULL;
            }
            if (wave == 0) dreg = diagT[Tn * 64 + lane];
        }
        __syncthreads();   // sup[] updates complete before next step A
    }
    for (int j = tid; j < NOUT; j += 1024) {
        bool s = (sup[j >> 6] >> (j & 63)) & 1ULL;
        float scv = scores_s[j];
        keep_out[j] = (!s && ((double)scv > 0.05)) ? 1.0f : 0.0f;
    }
}

extern "C" void kernel_launch(void* const* d_in, const int* in_sizes, int n_in,
                              void* d_out, int out_size, void* d_ws, size_t ws_size,
                              hipStream_t stream) {
    const float* cls0 = (const float*)d_in[0];
    const float* reg0 = (const float*)d_in[1];
    const float* ctn0 = (const float*)d_in[2];
    const float* cls1 = (const float*)d_in[3];
    const float* reg1 = (const float*)d_in[4];
    const float* ctn1 = (const float*)d_in[5];
    const float* cls2 = (const float*)d_in[6];
    const float* reg2 = (const float*)d_in[7];
    const float* ctn2 = (const float*)d_in[8];
    const float* scales = (const float*)d_in[9];

    char* ws = (char*)d_ws;
    int* hist = (int*)(ws + HIST_OFF);
    int* cnt  = (int*)(ws + CNT_OFF);
    unsigned long long* keys = (unsigned long long*)(ws + KEYS_OFF);
    int* labels = (int*)(ws + LAB_OFF);
    unsigned long long* sure = (unsigned long long*)(ws + SURE_OFF);
    unsigned long long* cand = (unsigned long long*)(ws + CAND_OFF);
    unsigned long long* surv = (unsigned long long*)(ws + SURV_OFF);
    unsigned long long* mask = (unsigned long long*)(ws + MASK_OFF);
    unsigned long long* diagT = (unsigned long long*)(ws + DIAG_OFF);
    float* out = (float*)d_out;

    hipMemsetAsync(ws, 0, MEMSET_BYTES, stream);

    score_kernel<<<(NPTS + 255) / 256, 256, 0, stream>>>(cls0, cls1, cls2, ctn0, ctn1, ctn2,
                                                         keys, labels, hist);
    thresh_kernel<<<3, 1024, 0, stream>>>(hist, cnt);
    compact_kernel<<<(NPTS + 255) / 256, 256, 0, stream>>>(keys, cnt, sure, cand);
    select_kernel<<<3, 1024, 0, stream>>>(cnt, sure, cand, surv);
    sort_emit_kernel<<<1, 1024, 0, stream>>>(surv, labels, reg0, reg1, reg2, scales, out);
    mask_kernel<<<(NOUT * NWORDS + 3) / 4, 256, 0, stream>>>(out, mask);
    diag_kernel<<<NTILE, 64, 0, stream>>>(out, diagT);
    nms_kernel<<<1, 1024, 0, stream>>>(mask, diagT, out + 12000, out + 18000);
}

// Round 7
// 396.043 us; speedup vs baseline: 1.6242x; 1.4268x over previous
//
#include <hip/hip_runtime.h>
#include <cmath>
#include <stdint.h>

#define NPTS   86016
#define NB     (1 << 14)     // histogram bins per level (f32 score bits >> 18)
#define K_TOP  1000
#define NOUT   3000
#define NWORDS 47            // ceil(3000/64)
#define CAND_CAP 16384
#define ECAP   8192          // edge capacity (expected E ~ hundreds)

// ---- workspace layout (bytes) ----
#define HIST_OFF   0
#define CNT_OFF    (NB * 3 * 4)                 // 196,608
// cnt[0..2]=sure_cnt  [3..5]=cand_cnt  [6..8]=binB  [9..11]=Rneed  [12]=edge_cnt
#define MEMSET_BYTES (CNT_OFF + 64)
#define KEYS_OFF   (CNT_OFF + 64)
#define LAB_OFF    (KEYS_OFF + NPTS * 8)
#define SURE_OFF   (LAB_OFF + NPTS * 4)
#define CAND_OFF   (SURE_OFF + 3 * 1024 * 8)
#define SURV_OFF   (CAND_OFF + 3 * CAND_CAP * 8)
#define EDGE_OFF   (SURV_OFF + NOUT * 8 + 64)   // ECAP*4

// stepwise-f32 sigmoid: CR f32 exp, then IEEE f32 add + div (matches numpy per-op chain)
__device__ __forceinline__ float sig_f32_stepwise(float x) {
    float e = (float)exp(-(double)x);   // correctly-rounded f32 exp(-x)
    return 1.0f / (1.0f + e);           // f32 add (CR), f32 div (CR)
}

// ---------------- kernel 1: f32 scores / labels / keys / histogram ----------------
__global__ void score_kernel(const float* __restrict__ cls0, const float* __restrict__ cls1,
                             const float* __restrict__ cls2,
                             const float* __restrict__ ctn0, const float* __restrict__ ctn1,
                             const float* __restrict__ ctn2,
                             unsigned long long* __restrict__ keys,
                             int* __restrict__ labels, int* __restrict__ hist) {
    int g = blockIdx.x * blockDim.x + threadIdx.x;
    if (g >= NPTS) return;
    int lv, p, HW;
    const float *cls, *ctn;
    if (g < 65536)      { lv = 0; p = g;         HW = 65536; cls = cls0; ctn = ctn0; }
    else if (g < 81920) { lv = 1; p = g - 65536; HW = 16384; cls = cls1; ctn = ctn1; }
    else                { lv = 2; p = g - 81920; HW = 4096;  cls = cls2; ctn = ctn2; }

    float sc = sig_f32_stepwise(ctn[p]);
    float best = -1.0f; int lab = 0;
    for (int c = 0; c < 80; c++) {
        float s  = sig_f32_stepwise(cls[c * HW + p]);
        float pr = s * sc;              // f32 mul
        float sj = __fsqrt_rn(pr);      // CR f32 sqrt == np.sqrt
        if (sj > best) { best = sj; lab = c; }  // first-occurrence argmax
    }
    unsigned int bits = __float_as_uint(best);  // score in (0,1]: positive -> bit order == value order
    unsigned long long key = ((unsigned long long)bits << 32) | (0xFFFFFFFFu - (unsigned)g);
    keys[g] = key;
    labels[g] = lab;
    atomicAdd(&hist[lv * NB + (int)(bits >> 18)], 1);
}

// ---------------- kernel 2: per-level cutoff bin via suffix scan ----------------
__global__ void thresh_kernel(const int* __restrict__ hist, int* __restrict__ cnt) {
    int lv = blockIdx.x, tid = threadIdx.x;
    const int* h = hist + lv * NB;
    __shared__ int part[1024];
    __shared__ int s_chunk, s_above;
    __shared__ int bins[17];

    int sum = 0;
    for (int k = 0; k < 16; k++) sum += h[tid * 16 + k];
    part[tid] = sum;
    __syncthreads();
    // suffix sums over 1024 chunk-partials
    for (int off = 1; off < 1024; off <<= 1) {
        int v = part[tid] + ((tid + off < 1024) ? part[tid + off] : 0);
        __syncthreads(); part[tid] = v; __syncthreads();
    }
    int nxt = (tid < 1023) ? part[tid + 1] : 0;
    if (part[tid] >= K_TOP && nxt < K_TOP) { s_chunk = tid; s_above = nxt; }
    __syncthreads();
    int chunk = s_chunk, above = s_above;

    if (tid < 16) bins[tid] = h[chunk * 16 + tid];
    __syncthreads();
    for (int off = 1; off < 16; off <<= 1) {
        int v = 0;
        if (tid < 16) v = bins[tid] + ((tid + off < 16) ? bins[tid + off] : 0);
        __syncthreads(); if (tid < 16) bins[tid] = v; __syncthreads();
    }
    if (tid < 16) {
        int ge    = above + bins[tid];
        int genxt = above + ((tid < 15) ? bins[tid + 1] : 0);
        if (ge >= K_TOP && genxt < K_TOP) {
            cnt[6 + lv] = chunk * 16 + tid;   // cutoff bin B
            cnt[9 + lv] = K_TOP - genxt;      // R needed from bin B
        }
    }
}

// ---------------- kernel 3: compact sure / candidate keys ----------------
__global__ void compact_kernel(const unsigned long long* __restrict__ keys,
                               int* __restrict__ cnt,
                               unsigned long long* __restrict__ sure,
                               unsigned long long* __restrict__ cand) {
    int g = blockIdx.x * blockDim.x + threadIdx.x;
    if (g >= NPTS) return;
    int lv = (g < 65536) ? 0 : (g < 81920 ? 1 : 2);
    unsigned long long key = keys[g];
    int bin = (int)(key >> 50);      // == f32 bits >> 18
    int B = cnt[6 + lv];
    if (bin > B) {
        int i = atomicAdd(&cnt[0 + lv], 1);
        sure[lv * 1024 + i] = key;
    } else if (bin == B) {
        int i = atomicAdd(&cnt[3 + lv], 1);
        if (i < CAND_CAP) cand[lv * CAND_CAP + i] = key;
    }
}

// ---------------- kernel 4: per-level candidate sort + build survivor set ----------------
__global__ void select_kernel(const int* __restrict__ cnt,
                              const unsigned long long* __restrict__ sure,
                              unsigned long long* __restrict__ cand,
                              unsigned long long* __restrict__ surv) {
    int lv = blockIdx.x, tid = threadIdx.x;
    unsigned long long* c = cand + lv * CAND_CAP;
    int n = cnt[3 + lv]; if (n > CAND_CAP) n = CAND_CAP;
    int R = cnt[9 + lv];
    int Ca = K_TOP - R;
    int m = 1; while (m < n) m <<= 1;
    for (int t = n + tid; t < m; t += 1024) c[t] = 0ULL;
    __syncthreads();
    for (int k = 2; k <= m; k <<= 1)
        for (int j = k >> 1; j > 0; j >>= 1) {
            for (int t = tid; t < m; t += 1024) {
                int l = t ^ j;
                if (l > t) {
                    unsigned long long a = c[t], b = c[l];
                    // descending sort: key encodes (score bits desc, index asc via 0xFFFFFFFF-g)
                    if (((t & k) == 0) ? (a < b) : (a > b)) { c[t] = b; c[l] = a; }
                }
            }
            __syncthreads();
        }
    for (int t = tid; t < Ca; t += 1024) surv[lv * K_TOP + t] = sure[lv * 1024 + t];
    for (int t = tid; t < R;  t += 1024) surv[lv * K_TOP + Ca + t] = c[t];
}

// ---------------- kernel 5: global sort of 3000 survivors + emit ----------------
__global__ void sort_emit_kernel(const unsigned long long* __restrict__ surv,
                                 const int* __restrict__ labels,
                                 const float* __restrict__ reg0, const float* __restrict__ reg1,
                                 const float* __restrict__ reg2,
                                 const float* __restrict__ scales,
                                 float* __restrict__ out) {
    __shared__ unsigned long long s[4096];
    int tid = threadIdx.x;
    for (int t = tid; t < 4096; t += 1024) s[t] = (t < NOUT) ? surv[t] : 0ULL;
    __syncthreads();
    for (int k = 2; k <= 4096; k <<= 1)
        for (int j = k >> 1; j > 0; j >>= 1) {
            for (int t = tid; t < 4096; t += 1024) {
                int l = t ^ j;
                if (l > t) {
                    unsigned long long a = s[t], b = s[l];
                    if (((t & k) == 0) ? (a < b) : (a > b)) { s[t] = b; s[l] = a; }
                }
            }
            __syncthreads();
        }
    for (int r = tid; r < NOUT; r += 1024) {
        unsigned long long key = s[r];
        unsigned int bits = (unsigned)(key >> 32);
        float score = __uint_as_float(bits);
        unsigned int g = 0xFFFFFFFFu - (unsigned)(key & 0xFFFFFFFFULL);
        int lv, p;
        if (g < 65536u)      { lv = 0; p = (int)g; }
        else if (g < 81920u) { lv = 1; p = (int)g - 65536; }
        else                 { lv = 2; p = (int)g - 81920; }
        const float* rp = (lv == 0) ? reg0 : ((lv == 1) ? reg1 : reg2);
        int HW = (lv == 0) ? 65536 : ((lv == 1) ? 16384 : 4096);
        int W = 256 >> lv;
        float strideF = (float)(8 << lv);
        float scale = scales[lv];
        int x = p & (W - 1);
        int y = p >> (8 - lv);
        // per-op f32 decode (matches numpy f32 chain exactly)
        float r0 = fmaxf(0.0f, rp[0 * HW + p] * scale) * strideF;
        float r1 = fmaxf(0.0f, rp[1 * HW + p] * scale) * strideF;
        float r2 = fmaxf(0.0f, rp[2 * HW + p] * scale) * strideF;
        float r3 = fmaxf(0.0f, rp[3 * HW + p] * scale) * strideF;
        float ax = ((float)x + 0.5f) * strideF;
        float ay = ((float)y + 0.5f) * strideF;
        out[r * 4 + 0] = ax - r0;
        out[r * 4 + 1] = ay - r1;
        out[r * 4 + 2] = ax + r2;
        out[r * 4 + 3] = ay + r3;
        out[12000 + r] = score;
        out[15000 + r] = (float)labels[g];
    }
}

// ---------------- kernel 6: sparse suppression-edge extraction ----------------
// all pairs i<j with IoU>0.6 (per-op f32 chain) -> packed (i<<12|j) appended atomically
__global__ void edge_kernel(const float* __restrict__ out,
                            unsigned* __restrict__ edges_g, int* __restrict__ cnt) {
    int j = blockIdx.y;
    int i = blockIdx.x * 256 + threadIdx.x;
    if (i >= j) return;                     // upper triangle only (j < NOUT by grid)
    float x1i = out[i * 4 + 0], y1i = out[i * 4 + 1];
    float x2i = out[i * 4 + 2], y2i = out[i * 4 + 3];
    float x1j = out[j * 4 + 0], y1j = out[j * 4 + 1];
    float x2j = out[j * 4 + 2], y2j = out[j * 4 + 3];
    float ai = (x2i - x1i) * (y2i - y1i);
    float aj = (x2j - x1j) * (y2j - y1j);
    float xx1 = fmaxf(x1i, x1j), yy1 = fmaxf(y1i, y1j);
    float xx2 = fminf(x2i, x2j), yy2 = fminf(y2i, y2j);
    float ww = fmaxf(1e-10f, xx2 - xx1);
    float hh = fmaxf(1e-10f, yy2 - yy1);
    float inter = ww * hh;
    float iou = inter / (((ai + aj) - inter) + 1e-14f);   // left-to-right f32, as numpy
    if ((double)iou > 0.6) {                              // f32 value vs python float 0.6
        int e = atomicAdd(&cnt[12], 1);
        if (e < ECAP) edges_g[e] = ((unsigned)i << 12) | (unsigned)j;
    }
}

// ---------------- kernel 7: sparse sequential NMS (single block) ----------------
// Sort edges ascending (source-major == greedy processing order), then one wave
// resolves the serial recursion: lane w holds sup word w in a register; per-chunk
// one shfl, per-edge one LDS broadcast read + ALU. No barriers in the chain.
__global__ __launch_bounds__(1024) void nms_sparse_kernel(
        const unsigned* __restrict__ edges_g,
        const int* __restrict__ cnt,
        const float* __restrict__ scores_s,
        float* __restrict__ keep_out) {
    __shared__ unsigned ed[ECAP];
    __shared__ unsigned long long supLds[NWORDS];
    int tid = threadIdx.x;
    int E = cnt[12]; if (E > ECAP) E = ECAP;
    int m = 1; while (m < E) m <<= 1;
    for (int t = tid; t < m; t += 1024) ed[t] = (t < E) ? edges_g[t] : 0xFFFFFFFFu;
    __syncthreads();
    // bitonic sort ascending (also removes atomic-append order nondeterminism)
    for (int k = 2; k <= m; k <<= 1)
        for (int j = k >> 1; j > 0; j >>= 1) {
            for (int t = tid; t < m; t += 1024) {
                int l = t ^ j;
                if (l > t) {
                    unsigned a = ed[t], b = ed[l];
                    if (((t & k) == 0) ? (a > b) : (a < b)) { ed[t] = b; ed[l] = a; }
                }
            }
            __syncthreads();
        }
    if (tid < 64) {
        int lane = tid;
        unsigned long long supW = 0ULL;   // lane w: suppression word w
        int ep = 0;
        for (int c = 0; c < NWORDS; c++) {
            unsigned long long cw = __shfl(supW, c, 64);  // complete: all sources < c*64 done
            int hi = (c + 1) * 64;
            while (ep < E) {
                unsigned k = ed[ep];                       // LDS broadcast (uniform)
                int i = (int)(k >> 12);
                if (i >= hi) break;
                int j = (int)(k & 4095);
                if (!((cw >> (i & 63)) & 1ULL)) {          // source i kept -> suppress j
                    if ((j >> 6) == c) cw |= 1ULL << (j & 63);
                    else if (lane == (j >> 6)) supW |= 1ULL << (j & 63);
                }
                ep++;
            }
            if (lane == c) supW = cw;
        }
        if (lane < NWORDS) supLds[lane] = supW;
    }
    __syncthreads();
    for (int j = tid; j < NOUT; j += 1024) {
        bool s = (supLds[j >> 6] >> (j & 63)) & 1ULL;
        float scv = scores_s[j];
        keep_out[j] = (!s && ((double)scv > 0.05)) ? 1.0f : 0.0f;
    }
}

extern "C" void kernel_launch(void* const* d_in, const int* in_sizes, int n_in,
                              void* d_out, int out_size, void* d_ws, size_t ws_size,
                              hipStream_t stream) {
    const float* cls0 = (const float*)d_in[0];
    const float* reg0 = (const float*)d_in[1];
    const float* ctn0 = (const float*)d_in[2];
    const float* cls1 = (const float*)d_in[3];
    const float* reg1 = (const float*)d_in[4];
    const float* ctn1 = (const float*)d_in[5];
    const float* cls2 = (const float*)d_in[6];
    const float* reg2 = (const float*)d_in[7];
    const float* ctn2 = (const float*)d_in[8];
    const float* scales = (const float*)d_in[9];

    char* ws = (char*)d_ws;
    int* hist = (int*)(ws + HIST_OFF);
    int* cnt  = (int*)(ws + CNT_OFF);
    unsigned long long* keys = (unsigned long long*)(ws + KEYS_OFF);
    int* labels = (int*)(ws + LAB_OFF);
    unsigned long long* sure = (unsigned long long*)(ws + SURE_OFF);
    unsigned long long* cand = (unsigned long long*)(ws + CAND_OFF);
    unsigned long long* surv = (unsigned long long*)(ws + SURV_OFF);
    unsigned* edges = (unsigned*)(ws + EDGE_OFF);
    float* out = (float*)d_out;

    hipMemsetAsync(ws, 0, MEMSET_BYTES, stream);

    score_kernel<<<(NPTS + 255) / 256, 256, 0, stream>>>(cls0, cls1, cls2, ctn0, ctn1, ctn2,
                                                         keys, labels, hist);
    thresh_kernel<<<3, 1024, 0, stream>>>(hist, cnt);
    compact_kernel<<<(NPTS + 255) / 256, 256, 0, stream>>>(keys, cnt, sure, cand);
    select_kernel<<<3, 1024, 0, stream>>>(cnt, sure, cand, surv);
    sort_emit_kernel<<<1, 1024, 0, stream>>>(surv, labels, reg0, reg1, reg2, scales, out);
    dim3 eg((NOUT + 255) / 256, NOUT);
    edge_kernel<<<eg, 256, 0, stream>>>(out, edges, cnt);
    nms_sparse_kernel<<<1, 1024, 0, stream>>>(edges, cnt, out + 12000, out + 18000);
}

// Round 8
// 383.296 us; speedup vs baseline: 1.6782x; 1.0333x over previous
//
#include <hip/hip_runtime.h>
#include <cmath>
#include <stdint.h>

#define NPTS   86016
#define NB     (1 << 14)     // histogram bins per level (f32 score bits >> 18)
#define K_TOP  1000
#define NOUT   3000
#define NWORDS 47            // ceil(3000/64)
#define CAND_CAP 16384
#define ECAP   8192          // edge capacity (expected E ~ hundreds)
#define FCAP   1024          // tie-flag capacity (expected ~20)

// ---- workspace layout (bytes) ----
#define HIST_OFF   0
#define CNT_OFF    (NB * 3 * 4)                 // 196,608
// cnt[0..2]=sure_cnt  [3..5]=cand_cnt  [6..8]=binB  [9..11]=Rneed  [12]=edge_cnt  [13]=flag_cnt
#define MEMSET_BYTES (CNT_OFF + 64)
#define KEYS_OFF   (CNT_OFF + 64)
#define LAB_OFF    (KEYS_OFF + NPTS * 8)
#define SURE_OFF   (LAB_OFF + NPTS * 4)
#define CAND_OFF   (SURE_OFF + 3 * 1024 * 8)
#define SURV_OFF   (CAND_OFF + 3 * CAND_CAP * 8)
#define EDGE_OFF   (SURV_OFF + NOUT * 8 + 64)   // ECAP*4
#define FLAG_OFF   (EDGE_OFF + ECAP * 4)        // FCAP*4

// stepwise-f32 sigmoid: CR f32 exp, then IEEE f32 add + div (matches numpy per-op chain)
__device__ __forceinline__ float sig_f32_stepwise(float x) {
    float e = (float)exp(-(double)x);   // correctly-rounded f32 exp(-x)
    return 1.0f / (1.0f + e);           // f32 add (CR), f32 div (CR)
}

__device__ __forceinline__ void locate(int g, int& lv, int& p, int& HW) {
    if (g < 65536)      { lv = 0; p = g;         HW = 65536; }
    else if (g < 81920) { lv = 1; p = g - 65536; HW = 16384; }
    else                { lv = 2; p = g - 81920; HW = 4096;  }
}

// ---------------- kernel 1: max-scan scores / labels / keys / histogram ----------------
// joint = sqrt(sig(cls)*sig(ctn)) is weakly monotone in cls (fixed ctn), so
// max_c joint = joint(max_c cls) and argmax resolves via (M,idx1,V) recurrence;
// f32-joint ties (joint(V)==joint(M)) are flagged for exact cleanup.
__global__ void score_kernel(const float* __restrict__ cls0, const float* __restrict__ cls1,
                             const float* __restrict__ cls2,
                             const float* __restrict__ ctn0, const float* __restrict__ ctn1,
                             const float* __restrict__ ctn2,
                             unsigned long long* __restrict__ keys,
                             int* __restrict__ labels, int* __restrict__ hist,
                             int* __restrict__ cnt, unsigned* __restrict__ flags) {
    int g = blockIdx.x * blockDim.x + threadIdx.x;
    if (g >= NPTS) return;
    int lv, p, HW;
    locate(g, lv, p, HW);
    const float* cls = (lv == 0) ? cls0 : ((lv == 1) ? cls1 : cls2);
    const float* ctn = (lv == 0) ? ctn0 : ((lv == 1) ? ctn1 : ctn2);

    // pure f32 max scan: m = running max, idx = first idx of m, v = max before idx
    float m = -INFINITY, v = -INFINITY; int idx = 0;
    for (int c = 0; c < 80; c++) {
        float x = cls[c * HW + p];          // independent loads -> ILP latency hiding
        if (x > m) { v = m; m = x; idx = c; }
    }
    float sc = sig_f32_stepwise(ctn[p]);
    float sM = sig_f32_stepwise(m);
    float jm = __fsqrt_rn(sM * sc);         // == max_c joint (monotonicity)
    float sV = sig_f32_stepwise(v);
    float jv = __fsqrt_rn(sV * sc);
    if (jv == jm) {                          // possible earlier-index tie: exact cleanup
        int f = atomicAdd(&cnt[13], 1);
        if (f < FCAP) flags[f] = (unsigned)g;
    }
    unsigned int bits = __float_as_uint(jm); // score in (0,1]: positive -> bit order == value order
    unsigned long long key = ((unsigned long long)bits << 32) | (0xFFFFFFFFu - (unsigned)g);
    keys[g] = key;
    labels[g] = idx;
    atomicAdd(&hist[lv * NB + (int)(bits >> 18)], 1);
}

// ---------------- kernel 1b: exact label cleanup for flagged (tied) points ----------------
__global__ void cleanup_kernel(const float* __restrict__ cls0, const float* __restrict__ cls1,
                               const float* __restrict__ cls2,
                               const float* __restrict__ ctn0, const float* __restrict__ ctn1,
                               const float* __restrict__ ctn2,
                               const int* __restrict__ cnt, const unsigned* __restrict__ flags,
                               int* __restrict__ labels) {
    int nf = cnt[13]; if (nf > FCAP) nf = FCAP;
    for (int t = threadIdx.x; t < nf; t += 256) {
        int g = (int)flags[t];
        int lv, p, HW;
        locate(g, lv, p, HW);
        const float* cls = (lv == 0) ? cls0 : ((lv == 1) ? cls1 : cls2);
        const float* ctn = (lv == 0) ? ctn0 : ((lv == 1) ? ctn1 : ctn2);
        float sc = sig_f32_stepwise(ctn[p]);
        float best = -1.0f; int lab = 0;
        for (int c = 0; c < 80; c++) {
            float s  = sig_f32_stepwise(cls[c * HW + p]);
            float sj = __fsqrt_rn(s * sc);
            if (sj > best) { best = sj; lab = c; }   // first-occurrence argmax
        }
        labels[g] = lab;
    }
}

// ---------------- kernel 2: per-level cutoff bin via suffix scan ----------------
__global__ void thresh_kernel(const int* __restrict__ hist, int* __restrict__ cnt) {
    int lv = blockIdx.x, tid = threadIdx.x;
    const int* h = hist + lv * NB;
    __shared__ int part[1024];
    __shared__ int s_chunk, s_above;
    __shared__ int bins[17];

    int sum = 0;
    for (int k = 0; k < 16; k++) sum += h[tid * 16 + k];
    part[tid] = sum;
    __syncthreads();
    for (int off = 1; off < 1024; off <<= 1) {
        int v = part[tid] + ((tid + off < 1024) ? part[tid + off] : 0);
        __syncthreads(); part[tid] = v; __syncthreads();
    }
    int nxt = (tid < 1023) ? part[tid + 1] : 0;
    if (part[tid] >= K_TOP && nxt < K_TOP) { s_chunk = tid; s_above = nxt; }
    __syncthreads();
    int chunk = s_chunk, above = s_above;

    if (tid < 16) bins[tid] = h[chunk * 16 + tid];
    __syncthreads();
    for (int off = 1; off < 16; off <<= 1) {
        int v = 0;
        if (tid < 16) v = bins[tid] + ((tid + off < 16) ? bins[tid + off] : 0);
        __syncthreads(); if (tid < 16) bins[tid] = v; __syncthreads();
    }
    if (tid < 16) {
        int ge    = above + bins[tid];
        int genxt = above + ((tid < 15) ? bins[tid + 1] : 0);
        if (ge >= K_TOP && genxt < K_TOP) {
            cnt[6 + lv] = chunk * 16 + tid;   // cutoff bin B
            cnt[9 + lv] = K_TOP - genxt;      // R needed from bin B
        }
    }
}

// ---------------- kernel 3: compact sure / candidate keys ----------------
__global__ void compact_kernel(const unsigned long long* __restrict__ keys,
                               int* __restrict__ cnt,
                               unsigned long long* __restrict__ sure,
                               unsigned long long* __restrict__ cand) {
    int g = blockIdx.x * blockDim.x + threadIdx.x;
    if (g >= NPTS) return;
    int lv = (g < 65536) ? 0 : (g < 81920 ? 1 : 2);
    unsigned long long key = keys[g];
    int bin = (int)(key >> 50);      // == f32 bits >> 18
    int B = cnt[6 + lv];
    if (bin > B) {
        int i = atomicAdd(&cnt[0 + lv], 1);
        sure[lv * 1024 + i] = key;
    } else if (bin == B) {
        int i = atomicAdd(&cnt[3 + lv], 1);
        if (i < CAND_CAP) cand[lv * CAND_CAP + i] = key;
    }
}

// ---------------- kernel 4: per-level candidate sort + build survivor set ----------------
__global__ void select_kernel(const int* __restrict__ cnt,
                              const unsigned long long* __restrict__ sure,
                              unsigned long long* __restrict__ cand,
                              unsigned long long* __restrict__ surv) {
    int lv = blockIdx.x, tid = threadIdx.x;
    unsigned long long* c = cand + lv * CAND_CAP;
    int n = cnt[3 + lv]; if (n > CAND_CAP) n = CAND_CAP;
    int R = cnt[9 + lv];
    int Ca = K_TOP - R;
    int m = 1; while (m < n) m <<= 1;
    for (int t = n + tid; t < m; t += 1024) c[t] = 0ULL;
    __syncthreads();
    for (int k = 2; k <= m; k <<= 1)
        for (int j = k >> 1; j > 0; j >>= 1) {
            for (int t = tid; t < m; t += 1024) {
                int l = t ^ j;
                if (l > t) {
                    unsigned long long a = c[t], b = c[l];
                    if (((t & k) == 0) ? (a < b) : (a > b)) { c[t] = b; c[l] = a; }
                }
            }
            __syncthreads();
        }
    for (int t = tid; t < Ca; t += 1024) surv[lv * K_TOP + t] = sure[lv * 1024 + t];
    for (int t = tid; t < R;  t += 1024) surv[lv * K_TOP + Ca + t] = c[t];
}

// ---------------- kernel 5: global sort of 3000 survivors + emit ----------------
__global__ void sort_emit_kernel(const unsigned long long* __restrict__ surv,
                                 const int* __restrict__ labels,
                                 const float* __restrict__ reg0, const float* __restrict__ reg1,
                                 const float* __restrict__ reg2,
                                 const float* __restrict__ scales,
                                 float* __restrict__ out) {
    __shared__ unsigned long long s[4096];
    int tid = threadIdx.x;
    for (int t = tid; t < 4096; t += 1024) s[t] = (t < NOUT) ? surv[t] : 0ULL;
    __syncthreads();
    for (int k = 2; k <= 4096; k <<= 1)
        for (int j = k >> 1; j > 0; j >>= 1) {
            for (int t = tid; t < 4096; t += 1024) {
                int l = t ^ j;
                if (l > t) {
                    unsigned long long a = s[t], b = s[l];
                    if (((t & k) == 0) ? (a < b) : (a > b)) { s[t] = b; s[l] = a; }
                }
            }
            __syncthreads();
        }
    for (int r = tid; r < NOUT; r += 1024) {
        unsigned long long key = s[r];
        unsigned int bits = (unsigned)(key >> 32);
        float score = __uint_as_float(bits);
        unsigned int g = 0xFFFFFFFFu - (unsigned)(key & 0xFFFFFFFFULL);
        int lv, p;
        if (g < 65536u)      { lv = 0; p = (int)g; }
        else if (g < 81920u) { lv = 1; p = (int)g - 65536; }
        else                 { lv = 2; p = (int)g - 81920; }
        const float* rp = (lv == 0) ? reg0 : ((lv == 1) ? reg1 : reg2);
        int HW = (lv == 0) ? 65536 : ((lv == 1) ? 16384 : 4096);
        int W = 256 >> lv;
        float strideF = (float)(8 << lv);
        float scale = scales[lv];
        int x = p & (W - 1);
        int y = p >> (8 - lv);
        float r0 = fmaxf(0.0f, rp[0 * HW + p] * scale) * strideF;
        float r1 = fmaxf(0.0f, rp[1 * HW + p] * scale) * strideF;
        float r2 = fmaxf(0.0f, rp[2 * HW + p] * scale) * strideF;
        float r3 = fmaxf(0.0f, rp[3 * HW + p] * scale) * strideF;
        float ax = ((float)x + 0.5f) * strideF;
        float ay = ((float)y + 0.5f) * strideF;
        out[r * 4 + 0] = ax - r0;
        out[r * 4 + 1] = ay - r1;
        out[r * 4 + 2] = ax + r2;
        out[r * 4 + 3] = ay + r3;
        out[12000 + r] = score;
        out[15000 + r] = (float)labels[g];
    }
}

// ---------------- kernel 6: sparse suppression-edge extraction ----------------
__global__ void edge_kernel(const float* __restrict__ out,
                            unsigned* __restrict__ edges_g, int* __restrict__ cnt) {
    int j = blockIdx.y;
    int i = blockIdx.x * 256 + threadIdx.x;
    if (i >= j) return;
    float x1i = out[i * 4 + 0], y1i = out[i * 4 + 1];
    float x2i = out[i * 4 + 2], y2i = out[i * 4 + 3];
    float x1j = out[j * 4 + 0], y1j = out[j * 4 + 1];
    float x2j = out[j * 4 + 2], y2j = out[j * 4 + 3];
    float ai = (x2i - x1i) * (y2i - y1i);
    float aj = (x2j - x1j) * (y2j - y1j);
    float xx1 = fmaxf(x1i, x1j), yy1 = fmaxf(y1i, y1j);
    float xx2 = fminf(x2i, x2j), yy2 = fminf(y2i, y2j);
    float ww = fmaxf(1e-10f, xx2 - xx1);
    float hh = fmaxf(1e-10f, yy2 - yy1);
    float inter = ww * hh;
    float iou = inter / (((ai + aj) - inter) + 1e-14f);
    if ((double)iou > 0.6) {
        int e = atomicAdd(&cnt[12], 1);
        if (e < ECAP) edges_g[e] = ((unsigned)i << 12) | (unsigned)j;
    }
}

// ---------------- kernel 7: sparse sequential NMS (single block) ----------------
__global__ __launch_bounds__(1024) void nms_sparse_kernel(
        const unsigned* __restrict__ edges_g,
        const int* __restrict__ cnt,
        const float* __restrict__ scores_s,
        float* __restrict__ keep_out) {
    __shared__ unsigned ed[ECAP];
    __shared__ unsigned long long supLds[NWORDS];
    int tid = threadIdx.x;
    int E = cnt[12]; if (E > ECAP) E = ECAP;
    int m = 1; while (m < E) m <<= 1;
    for (int t = tid; t < m; t += 1024) ed[t] = (t < E) ? edges_g[t] : 0xFFFFFFFFu;
    __syncthreads();
    for (int k = 2; k <= m; k <<= 1)
        for (int j = k >> 1; j > 0; j >>= 1) {
            for (int t = tid; t < m; t += 1024) {
                int l = t ^ j;
                if (l > t) {
                    unsigned a = ed[t], b = ed[l];
                    if (((t & k) == 0) ? (a > b) : (a < b)) { ed[t] = b; ed[l] = a; }
                }
            }
            __syncthreads();
        }
    if (tid < 64) {
        int lane = tid;
        unsigned long long supW = 0ULL;
        int ep = 0;
        for (int c = 0; c < NWORDS; c++) {
            unsigned long long cw = __shfl(supW, c, 64);
            int hi = (c + 1) * 64;
            while (ep < E) {
                unsigned k = ed[ep];
                int i = (int)(k >> 12);
                if (i >= hi) break;
                int j = (int)(k & 4095);
                if (!((cw >> (i & 63)) & 1ULL)) {
                    if ((j >> 6) == c) cw |= 1ULL << (j & 63);
                    else if (lane == (j >> 6)) supW |= 1ULL << (j & 63);
                }
                ep++;
            }
            if (lane == c) supW = cw;
        }
        if (lane < NWORDS) supLds[lane] = supW;
    }
    __syncthreads();
    for (int j = tid; j < NOUT; j += 1024) {
        bool s = (supLds[j >> 6] >> (j & 63)) & 1ULL;
        float scv = scores_s[j];
        keep_out[j] = (!s && ((double)scv > 0.05)) ? 1.0f : 0.0f;
    }
}

extern "C" void kernel_launch(void* const* d_in, const int* in_sizes, int n_in,
                              void* d_out, int out_size, void* d_ws, size_t ws_size,
                              hipStream_t stream) {
    const float* cls0 = (const float*)d_in[0];
    const float* reg0 = (const float*)d_in[1];
    const float* ctn0 = (const float*)d_in[2];
    const float* cls1 = (const float*)d_in[3];
    const float* reg1 = (const float*)d_in[4];
    const float* ctn1 = (const float*)d_in[5];
    const float* cls2 = (const float*)d_in[6];
    const float* reg2 = (const float*)d_in[7];
    const float* ctn2 = (const float*)d_in[8];
    const float* scales = (const float*)d_in[9];

    char* ws = (char*)d_ws;
    int* hist = (int*)(ws + HIST_OFF);
    int* cnt  = (int*)(ws + CNT_OFF);
    unsigned long long* keys = (unsigned long long*)(ws + KEYS_OFF);
    int* labels = (int*)(ws + LAB_OFF);
    unsigned long long* sure = (unsigned long long*)(ws + SURE_OFF);
    unsigned long long* cand = (unsigned long long*)(ws + CAND_OFF);
    unsigned long long* surv = (unsigned long long*)(ws + SURV_OFF);
    unsigned* edges = (unsigned*)(ws + EDGE_OFF);
    unsigned* flags = (unsigned*)(ws + FLAG_OFF);
    float* out = (float*)d_out;

    hipMemsetAsync(ws, 0, MEMSET_BYTES, stream);

    score_kernel<<<(NPTS + 255) / 256, 256, 0, stream>>>(cls0, cls1, cls2, ctn0, ctn1, ctn2,
                                                         keys, labels, hist, cnt, flags);
    cleanup_kernel<<<1, 256, 0, stream>>>(cls0, cls1, cls2, ctn0, ctn1, ctn2, cnt, flags, labels);
    thresh_kernel<<<3, 1024, 0, stream>>>(hist, cnt);
    compact_kernel<<<(NPTS + 255) / 256, 256, 0, stream>>>(keys, cnt, sure, cand);
    select_kernel<<<3, 1024, 0, stream>>>(cnt, sure, cand, surv);
    sort_emit_kernel<<<1, 1024, 0, stream>>>(surv, labels, reg0, reg1, reg2, scales, out);
    dim3 eg((NOUT + 255) / 256, NOUT);
    edge_kernel<<<eg, 256, 0, stream>>>(out, edges, cnt);
    nms_sparse_kernel<<<1, 1024, 0, stream>>>(edges, cnt, out + 12000, out + 18000);
}

// Round 9
// 279.174 us; speedup vs baseline: 2.3041x; 1.3730x over previous
//
#include <hip/hip_runtime.h>
#include <cmath>
#include <stdint.h>

#define NPTS   86016
#define NB     (1 << 18)     // histogram bins per level (f32 score bits >> 12)
#define K_TOP  1000
#define NOUT   3000
#define NWORDS 47            // ceil(3000/64)
#define CAND_CAP 16384
#define ECAP   8192          // edge capacity (expected E ~ hundreds)
#define FCAP   1024          // tie-flag capacity (expected ~20)
#define NCHUNK 5             // class chunks (5 x 16 = 80)

// ---- workspace layout (bytes) ----
#define HIST_OFF   0
#define CNT_OFF    (NB * 3 * 4)                 // 3,145,728
// cnt[0..2]=sure_cnt  [3..5]=cand_cnt  [6..8]=binB  [9..11]=Rneed  [12]=edge_cnt  [13]=flag_cnt
#define MEMSET_BYTES (CNT_OFF + 64)
#define KEYS_OFF   (CNT_OFF + 64)
#define LAB_OFF    (KEYS_OFF + NPTS * 8)
#define SURE_OFF   (LAB_OFF + NPTS * 4)
#define CAND_OFF   (SURE_OFF + 3 * 1024 * 8)
#define SURV_OFF   (CAND_OFF + 3 * CAND_CAP * 8)
#define EDGE_OFF   (SURV_OFF + NOUT * 8 + 64)   // ECAP*4
#define FLAG_OFF   (EDGE_OFF + ECAP * 4)        // FCAP*4
#define PM_OFF     (FLAG_OFF + FCAP * 4)        // NCHUNK*NPTS*4
#define PV_OFF     (PM_OFF + NCHUNK * NPTS * 4) // NCHUNK*NPTS*4
#define PIDX_OFF   (PV_OFF + NCHUNK * NPTS * 4) // NCHUNK*NPTS*4

// stepwise-f32 sigmoid: CR f32 exp, then IEEE f32 add + div (matches numpy per-op chain)
__device__ __forceinline__ float sig_f32_stepwise(float x) {
    float e = (float)exp(-(double)x);   // correctly-rounded f32 exp(-x)
    return 1.0f / (1.0f + e);           // f32 add (CR), f32 div (CR)
}

__device__ __forceinline__ void locate(int g, int& lv, int& p, int& HW) {
    if (g < 65536)      { lv = 0; p = g;         HW = 65536; }
    else if (g < 81920) { lv = 1; p = g - 65536; HW = 16384; }
    else                { lv = 2; p = g - 81920; HW = 4096;  }
}

// ---------------- kernel 1a: per-chunk max scan (16 classes, reg-resident) ----------------
__global__ void partial_kernel(const float* __restrict__ cls0, const float* __restrict__ cls1,
                               const float* __restrict__ cls2,
                               float* __restrict__ pm, float* __restrict__ pv,
                               int* __restrict__ pidx) {
    int g = blockIdx.x * blockDim.x + threadIdx.x;
    if (g >= NPTS) return;
    int chunk = blockIdx.y;
    int lv, p, HW;
    locate(g, lv, p, HW);
    const float* cls = (lv == 0) ? cls0 : ((lv == 1) ? cls1 : cls2);
    const float* base = cls + (size_t)chunk * 16 * HW + p;
    float x[16];
#pragma unroll
    for (int c = 0; c < 16; c++) x[c] = base[(size_t)c * HW];   // 16 independent loads (MLP)
    float m = -INFINITY, v = -INFINITY; int idx = 0;
#pragma unroll
    for (int c = 0; c < 16; c++)
        if (x[c] > m) { v = m; m = x[c]; idx = chunk * 16 + c; }  // first-occurrence (strict >)
    pm[chunk * NPTS + g] = m;
    pv[chunk * NPTS + g] = v;
    pidx[chunk * NPTS + g] = idx;
}

// ---------------- kernel 1b: combine partials, scores / labels / keys / histogram ----------
// joint = sqrt(sig(cls)*sig(ctn)) is weakly monotone in cls, so max_c joint = joint(max_c cls);
// v = max over classes with index < idx; f32-joint tie (joint(v)==joint(m)) -> exact cleanup.
__global__ void combine_kernel(const float* __restrict__ ctn0, const float* __restrict__ ctn1,
                               const float* __restrict__ ctn2,
                               const float* __restrict__ pm, const float* __restrict__ pv,
                               const int* __restrict__ pidx,
                               unsigned long long* __restrict__ keys,
                               int* __restrict__ labels, int* __restrict__ hist,
                               int* __restrict__ cnt, unsigned* __restrict__ flags) {
    int g = blockIdx.x * blockDim.x + threadIdx.x;
    if (g >= NPTS) return;
    int lv, p, HW;
    locate(g, lv, p, HW);
    const float* ctn = (lv == 0) ? ctn0 : ((lv == 1) ? ctn1 : ctn2);

    float m = -INFINITY, v = -INFINITY; int idx = 0;
#pragma unroll
    for (int k = 0; k < NCHUNK; k++) {
        float bm = pm[k * NPTS + g];
        float bv = pv[k * NPTS + g];
        int bidx = pidx[k * NPTS + g];
        if (bm > m) { v = fmaxf(m, bv); m = bm; idx = bidx; }
        // else: chunk k's classes are all after idx -> v unchanged
    }
    float sc = sig_f32_stepwise(ctn[p]);
    float sM = sig_f32_stepwise(m);
    float jm = __fsqrt_rn(sM * sc);          // == max_c joint (monotonicity)
    float sV = sig_f32_stepwise(v);
    float jv = __fsqrt_rn(sV * sc);
    if (jv == jm) {                           // possible earlier-index label tie
        int f = atomicAdd(&cnt[13], 1);
        if (f < FCAP) flags[f] = (unsigned)g;
    }
    unsigned int bits = __float_as_uint(jm);  // positive -> bit order == value order
    unsigned long long key = ((unsigned long long)bits << 32) | (0xFFFFFFFFu - (unsigned)g);
    keys[g] = key;
    labels[g] = idx;
    atomicAdd(&hist[lv * NB + (int)(bits >> 12)], 1);
}

// ---------------- kernel 1c: exact label cleanup for flagged (tied) points ----------------
__global__ void cleanup_kernel(const float* __restrict__ cls0, const float* __restrict__ cls1,
                               const float* __restrict__ cls2,
                               const float* __restrict__ ctn0, const float* __restrict__ ctn1,
                               const float* __restrict__ ctn2,
                               const int* __restrict__ cnt, const unsigned* __restrict__ flags,
                               int* __restrict__ labels) {
    int nf = cnt[13]; if (nf > FCAP) nf = FCAP;
    for (int t = threadIdx.x; t < nf; t += 256) {
        int g = (int)flags[t];
        int lv, p, HW;
        locate(g, lv, p, HW);
        const float* cls = (lv == 0) ? cls0 : ((lv == 1) ? cls1 : cls2);
        const float* ctn = (lv == 0) ? ctn0 : ((lv == 1) ? ctn1 : ctn2);
        float sc = sig_f32_stepwise(ctn[p]);
        float best = -1.0f; int lab = 0;
        for (int c = 0; c < 80; c++) {
            float s  = sig_f32_stepwise(cls[c * HW + p]);
            float sj = __fsqrt_rn(s * sc);
            if (sj > best) { best = sj; lab = c; }   // first-occurrence argmax
        }
        labels[g] = lab;
    }
}

// ---------------- kernel 2: per-level cutoff bin via suffix scan ----------------
__global__ void thresh_kernel(const int* __restrict__ hist, int* __restrict__ cnt) {
    int lv = blockIdx.x, tid = threadIdx.x;
    const int* h = hist + lv * NB;
    __shared__ int part[1024];
    __shared__ int s_chunk, s_above;
    __shared__ int bins[257];

    // each thread owns 256 bins, read as 64 independent int4 loads (MLP)
    const int4* h4 = (const int4*)(h + tid * 256);
    int sum = 0;
#pragma unroll 16
    for (int k = 0; k < 64; k++) { int4 q = h4[k]; sum += q.x + q.y + q.z + q.w; }
    part[tid] = sum;
    __syncthreads();
    for (int off = 1; off < 1024; off <<= 1) {
        int v = part[tid] + ((tid + off < 1024) ? part[tid + off] : 0);
        __syncthreads(); part[tid] = v; __syncthreads();
    }
    int nxt = (tid < 1023) ? part[tid + 1] : 0;
    if (part[tid] >= K_TOP && nxt < K_TOP) { s_chunk = tid; s_above = nxt; }
    __syncthreads();
    int chunk = s_chunk, above = s_above;

    if (tid < 256) bins[tid] = h[chunk * 256 + tid];
    __syncthreads();
    for (int off = 1; off < 256; off <<= 1) {
        int v = 0;
        if (tid < 256) v = bins[tid] + ((tid + off < 256) ? bins[tid + off] : 0);
        __syncthreads(); if (tid < 256) bins[tid] = v; __syncthreads();
    }
    if (tid < 256) {
        int ge    = above + bins[tid];
        int genxt = above + ((tid < 255) ? bins[tid + 1] : 0);
        if (ge >= K_TOP && genxt < K_TOP) {
            cnt[6 + lv] = chunk * 256 + tid;  // cutoff bin B
            cnt[9 + lv] = K_TOP - genxt;      // R needed from bin B
        }
    }
}

// ---------------- kernel 3: compact sure / candidate keys ----------------
__global__ void compact_kernel(const unsigned long long* __restrict__ keys,
                               int* __restrict__ cnt,
                               unsigned long long* __restrict__ sure,
                               unsigned long long* __restrict__ cand) {
    int g = blockIdx.x * blockDim.x + threadIdx.x;
    if (g >= NPTS) return;
    int lv = (g < 65536) ? 0 : (g < 81920 ? 1 : 2);
    unsigned long long key = keys[g];
    int bin = (int)(key >> 44);      // == f32 bits >> 12
    int B = cnt[6 + lv];
    if (bin > B) {
        int i = atomicAdd(&cnt[0 + lv], 1);
        sure[lv * 1024 + i] = key;
    } else if (bin == B) {
        int i = atomicAdd(&cnt[3 + lv], 1);
        if (i < CAND_CAP) cand[lv * CAND_CAP + i] = key;
    }
}

// ---------------- kernel 4: per-level candidate sort + build survivor set ----------------
__global__ void select_kernel(const int* __restrict__ cnt,
                              const unsigned long long* __restrict__ sure,
                              unsigned long long* __restrict__ cand,
                              unsigned long long* __restrict__ surv) {
    int lv = blockIdx.x, tid = threadIdx.x;
    unsigned long long* c = cand + lv * CAND_CAP;
    int n = cnt[3 + lv]; if (n > CAND_CAP) n = CAND_CAP;
    int R = cnt[9 + lv];
    int Ca = K_TOP - R;
    int m = 1; while (m < n) m <<= 1;
    for (int t = n + tid; t < m; t += 1024) c[t] = 0ULL;
    __syncthreads();
    for (int k = 2; k <= m; k <<= 1)
        for (int j = k >> 1; j > 0; j >>= 1) {
            for (int t = tid; t < m; t += 1024) {
                int l = t ^ j;
                if (l > t) {
                    unsigned long long a = c[t], b = c[l];
                    if (((t & k) == 0) ? (a < b) : (a > b)) { c[t] = b; c[l] = a; }
                }
            }
            __syncthreads();
        }
    for (int t = tid; t < Ca; t += 1024) surv[lv * K_TOP + t] = sure[lv * 1024 + t];
    for (int t = tid; t < R;  t += 1024) surv[lv * K_TOP + Ca + t] = c[t];
}

// ---------------- kernel 5: global sort of 3000 survivors + emit ----------------
__global__ void sort_emit_kernel(const unsigned long long* __restrict__ surv,
                                 const int* __restrict__ labels,
                                 const float* __restrict__ reg0, const float* __restrict__ reg1,
                                 const float* __restrict__ reg2,
                                 const float* __restrict__ scales,
                                 float* __restrict__ out) {
    __shared__ unsigned long long s[4096];
    int tid = threadIdx.x;
    for (int t = tid; t < 4096; t += 1024) s[t] = (t < NOUT) ? surv[t] : 0ULL;
    __syncthreads();
    for (int k = 2; k <= 4096; k <<= 1)
        for (int j = k >> 1; j > 0; j >>= 1) {
            for (int t = tid; t < 4096; t += 1024) {
                int l = t ^ j;
                if (l > t) {
                    unsigned long long a = s[t], b = s[l];
                    if (((t & k) == 0) ? (a < b) : (a > b)) { s[t] = b; s[l] = a; }
                }
            }
            __syncthreads();
        }
    for (int r = tid; r < NOUT; r += 1024) {
        unsigned long long key = s[r];
        unsigned int bits = (unsigned)(key >> 32);
        float score = __uint_as_float(bits);
        unsigned int g = 0xFFFFFFFFu - (unsigned)(key & 0xFFFFFFFFULL);
        int lv, p;
        if (g < 65536u)      { lv = 0; p = (int)g; }
        else if (g < 81920u) { lv = 1; p = (int)g - 65536; }
        else                 { lv = 2; p = (int)g - 81920; }
        const float* rp = (lv == 0) ? reg0 : ((lv == 1) ? reg1 : reg2);
        int HW = (lv == 0) ? 65536 : ((lv == 1) ? 16384 : 4096);
        int W = 256 >> lv;
        float strideF = (float)(8 << lv);
        float scale = scales[lv];
        int x = p & (W - 1);
        int y = p >> (8 - lv);
        float r0 = fmaxf(0.0f, rp[0 * HW + p] * scale) * strideF;
        float r1 = fmaxf(0.0f, rp[1 * HW + p] * scale) * strideF;
        float r2 = fmaxf(0.0f, rp[2 * HW + p] * scale) * strideF;
        float r3 = fmaxf(0.0f, rp[3 * HW + p] * scale) * strideF;
        float ax = ((float)x + 0.5f) * strideF;
        float ay = ((float)y + 0.5f) * strideF;
        out[r * 4 + 0] = ax - r0;
        out[r * 4 + 1] = ay - r1;
        out[r * 4 + 2] = ax + r2;
        out[r * 4 + 3] = ay + r3;
        out[12000 + r] = score;
        out[15000 + r] = (float)labels[g];
    }
}

// ---------------- kernel 6: sparse suppression-edge extraction ----------------
__global__ void edge_kernel(const float* __restrict__ out,
                            unsigned* __restrict__ edges_g, int* __restrict__ cnt) {
    int j = blockIdx.y;
    int i = blockIdx.x * 1024 + threadIdx.x;
    if (i >= j) return;
    float x1i = out[i * 4 + 0], y1i = out[i * 4 + 1];
    float x2i = out[i * 4 + 2], y2i = out[i * 4 + 3];
    float x1j = out[j * 4 + 0], y1j = out[j * 4 + 1];
    float x2j = out[j * 4 + 2], y2j = out[j * 4 + 3];
    float ai = (x2i - x1i) * (y2i - y1i);
    float aj = (x2j - x1j) * (y2j - y1j);
    float xx1 = fmaxf(x1i, x1j), yy1 = fmaxf(y1i, y1j);
    float xx2 = fminf(x2i, x2j), yy2 = fminf(y2i, y2j);
    float ww = fmaxf(1e-10f, xx2 - xx1);
    float hh = fmaxf(1e-10f, yy2 - yy1);
    float inter = ww * hh;
    float iou = inter / (((ai + aj) - inter) + 1e-14f);
    if ((double)iou > 0.6) {
        int e = atomicAdd(&cnt[12], 1);
        if (e < ECAP) edges_g[e] = ((unsigned)i << 12) | (unsigned)j;
    }
}

// ---------------- kernel 7: sparse sequential NMS (single block) ----------------
__global__ __launch_bounds__(1024) void nms_sparse_kernel(
        const unsigned* __restrict__ edges_g,
        const int* __restrict__ cnt,
        const float* __restrict__ scores_s,
        float* __restrict__ keep_out) {
    __shared__ unsigned ed[ECAP];
    __shared__ unsigned long long supLds[NWORDS];
    int tid = threadIdx.x;
    int E = cnt[12]; if (E > ECAP) E = ECAP;
    int m = 1; while (m < E) m <<= 1;
    for (int t = tid; t < m; t += 1024) ed[t] = (t < E) ? edges_g[t] : 0xFFFFFFFFu;
    __syncthreads();
    for (int k = 2; k <= m; k <<= 1)
        for (int j = k >> 1; j > 0; j >>= 1) {
            for (int t = tid; t < m; t += 1024) {
                int l = t ^ j;
                if (l > t) {
                    unsigned a = ed[t], b = ed[l];
                    if (((t & k) == 0) ? (a > b) : (a < b)) { ed[t] = b; ed[l] = a; }
                }
            }
            __syncthreads();
        }
    if (tid < 64) {
        int lane = tid;
        unsigned long long supW = 0ULL;
        int ep = 0;
        for (int c = 0; c < NWORDS; c++) {
            unsigned long long cw = __shfl(supW, c, 64);
            int hi = (c + 1) * 64;
            while (ep < E) {
                unsigned k = ed[ep];
                int i = (int)(k >> 12);
                if (i >= hi) break;
                int j = (int)(k & 4095);
                if (!((cw >> (i & 63)) & 1ULL)) {
                    if ((j >> 6) == c) cw |= 1ULL << (j & 63);
                    else if (lane == (j >> 6)) supW |= 1ULL << (j & 63);
                }
                ep++;
            }
            if (lane == c) supW = cw;
        }
        if (lane < NWORDS) supLds[lane] = supW;
    }
    __syncthreads();
    for (int j = tid; j < NOUT; j += 1024) {
        bool s = (supLds[j >> 6] >> (j & 63)) & 1ULL;
        float scv = scores_s[j];
        keep_out[j] = (!s && ((double)scv > 0.05)) ? 1.0f : 0.0f;
    }
}

extern "C" void kernel_launch(void* const* d_in, const int* in_sizes, int n_in,
                              void* d_out, int out_size, void* d_ws, size_t ws_size,
                              hipStream_t stream) {
    const float* cls0 = (const float*)d_in[0];
    const float* reg0 = (const float*)d_in[1];
    const float* ctn0 = (const float*)d_in[2];
    const float* cls1 = (const float*)d_in[3];
    const float* reg1 = (const float*)d_in[4];
    const float* ctn1 = (const float*)d_in[5];
    const float* cls2 = (const float*)d_in[6];
    const float* reg2 = (const float*)d_in[7];
    const float* ctn2 = (const float*)d_in[8];
    const float* scales = (const float*)d_in[9];

    char* ws = (char*)d_ws;
    int* hist = (int*)(ws + HIST_OFF);
    int* cnt  = (int*)(ws + CNT_OFF);
    unsigned long long* keys = (unsigned long long*)(ws + KEYS_OFF);
    int* labels = (int*)(ws + LAB_OFF);
    unsigned long long* sure = (unsigned long long*)(ws + SURE_OFF);
    unsigned long long* cand = (unsigned long long*)(ws + CAND_OFF);
    unsigned long long* surv = (unsigned long long*)(ws + SURV_OFF);
    unsigned* edges = (unsigned*)(ws + EDGE_OFF);
    unsigned* flags = (unsigned*)(ws + FLAG_OFF);
    float* pm = (float*)(ws + PM_OFF);
    float* pv = (float*)(ws + PV_OFF);
    int* pidx = (int*)(ws + PIDX_OFF);
    float* out = (float*)d_out;

    hipMemsetAsync(ws, 0, MEMSET_BYTES, stream);

    dim3 pg((NPTS + 255) / 256, NCHUNK);
    partial_kernel<<<pg, 256, 0, stream>>>(cls0, cls1, cls2, pm, pv, pidx);
    combine_kernel<<<(NPTS + 255) / 256, 256, 0, stream>>>(ctn0, ctn1, ctn2, pm, pv, pidx,
                                                           keys, labels, hist, cnt, flags);
    cleanup_kernel<<<1, 256, 0, stream>>>(cls0, cls1, cls2, ctn0, ctn1, ctn2, cnt, flags, labels);
    thresh_kernel<<<3, 1024, 0, stream>>>(hist, cnt);
    compact_kernel<<<(NPTS + 255) / 256, 256, 0, stream>>>(keys, cnt, sure, cand);
    select_kernel<<<3, 1024, 0, stream>>>(cnt, sure, cand, surv);
    sort_emit_kernel<<<1, 1024, 0, stream>>>(surv, labels, reg0, reg1, reg2, scales, out);
    dim3 eg((NOUT + 1023) / 1024, NOUT);
    edge_kernel<<<eg, 1024, 0, stream>>>(out, edges, cnt);
    nms_sparse_kernel<<<1, 1024, 0, stream>>>(edges, cnt, out + 12000, out + 18000);
}

// Round 10
// 235.105 us; speedup vs baseline: 2.7360x; 1.1874x over previous
//
#include <hip/hip_runtime.h>
#include <cmath>
#include <stdint.h>

#define NPTS   86016
#define NB     (1 << 18)     // histogram bins per level (f32 score bits >> 12)
#define K_TOP  1000
#define NOUT   3000
#define NWORDS 47            // ceil(3000/64)
#define CAND_CAP 16384
#define ECAP   8192          // edge capacity (expected E ~ hundreds)
#define FCAP   1024          // tie-flag capacity (expected ~20)
#define NCHUNK 5             // class chunks (5 x 16 = 80)

// ---- workspace layout (bytes) ----
#define HIST_OFF   0
#define CNT_OFF    (NB * 3 * 4)                 // 3,145,728
// cnt[0..2]=sure_cnt  [3..5]=cand_cnt  [6..8]=binB  [9..11]=Rneed  [12]=edge_cnt  [13]=flag_cnt
#define KEYS_OFF   (CNT_OFF + 64)
#define LAB_OFF    (KEYS_OFF + NPTS * 8)
#define SURE_OFF   (LAB_OFF + NPTS * 4)
#define CAND_OFF   (SURE_OFF + 3 * 1024 * 8)
#define SURV_OFF   (CAND_OFF + 3 * CAND_CAP * 8)
#define EDGE_OFF   (SURV_OFF + NOUT * 8 + 64)   // ECAP*4
#define FLAG_OFF   (EDGE_OFF + ECAP * 4)        // FCAP*4
#define PM_OFF     (FLAG_OFF + FCAP * 4)        // NCHUNK*NPTS*4
#define PV_OFF     (PM_OFF + NCHUNK * NPTS * 4) // NCHUNK*NPTS*4
#define PIDX_OFF   (PV_OFF + NCHUNK * NPTS * 4) // NCHUNK*NPTS*4

// stepwise-f32 sigmoid: CR f32 exp, then IEEE f32 add + div (matches numpy per-op chain)
__device__ __forceinline__ float sig_f32_stepwise(float x) {
    float e = (float)exp(-(double)x);   // correctly-rounded f32 exp(-x)
    return 1.0f / (1.0f + e);           // f32 add (CR), f32 div (CR)
}

__device__ __forceinline__ void locate(int g, int& lv, int& p, int& HW) {
    if (g < 65536)      { lv = 0; p = g;         HW = 65536; }
    else if (g < 81920) { lv = 1; p = g - 65536; HW = 16384; }
    else                { lv = 2; p = g - 81920; HW = 4096;  }
}

// ---------------- kernel 1a: per-chunk max scan + hist/cnt clear ----------------
__global__ void partial_kernel(const float* __restrict__ cls0, const float* __restrict__ cls1,
                               const float* __restrict__ cls2,
                               float* __restrict__ pm, float* __restrict__ pv,
                               int* __restrict__ pidx, int* __restrict__ histbase) {
    // distributed clear of hist (3*NB ints) + cnt (16 ints), before any consumer kernel
    int nblocks = gridDim.x * gridDim.y;
    int bid = blockIdx.y * gridDim.x + blockIdx.x;
    int nthreads = nblocks * 256;
    for (int idx = bid * 256 + threadIdx.x; idx < 3 * NB + 16; idx += nthreads)
        histbase[idx] = 0;

    int g = blockIdx.x * blockDim.x + threadIdx.x;
    if (g >= NPTS) return;
    int chunk = blockIdx.y;
    int lv, p, HW;
    locate(g, lv, p, HW);
    const float* cls = (lv == 0) ? cls0 : ((lv == 1) ? cls1 : cls2);
    const float* base = cls + (size_t)chunk * 16 * HW + p;
    float x[16];
#pragma unroll
    for (int c = 0; c < 16; c++) x[c] = base[(size_t)c * HW];   // 16 independent loads (MLP)
    float m = -INFINITY, v = -INFINITY; int idx = 0;
#pragma unroll
    for (int c = 0; c < 16; c++)
        if (x[c] > m) { v = m; m = x[c]; idx = chunk * 16 + c; }  // first-occurrence (strict >)
    pm[chunk * NPTS + g] = m;
    pv[chunk * NPTS + g] = v;
    pidx[chunk * NPTS + g] = idx;
}

// ---------------- kernel 1b: combine partials, scores / labels / keys / histogram ----------
__global__ void combine_kernel(const float* __restrict__ ctn0, const float* __restrict__ ctn1,
                               const float* __restrict__ ctn2,
                               const float* __restrict__ pm, const float* __restrict__ pv,
                               const int* __restrict__ pidx,
                               unsigned long long* __restrict__ keys,
                               int* __restrict__ labels, int* __restrict__ hist,
                               int* __restrict__ cnt, unsigned* __restrict__ flags) {
    int g = blockIdx.x * blockDim.x + threadIdx.x;
    if (g >= NPTS) return;
    int lv, p, HW;
    locate(g, lv, p, HW);
    const float* ctn = (lv == 0) ? ctn0 : ((lv == 1) ? ctn1 : ctn2);

    float m = -INFINITY, v = -INFINITY; int idx = 0;
#pragma unroll
    for (int k = 0; k < NCHUNK; k++) {
        float bm = pm[k * NPTS + g];
        float bv = pv[k * NPTS + g];
        int bidx = pidx[k * NPTS + g];
        if (bm > m) { v = fmaxf(m, bv); m = bm; idx = bidx; }
    }
    float sc = sig_f32_stepwise(ctn[p]);
    float sM = sig_f32_stepwise(m);
    float jm = __fsqrt_rn(sM * sc);          // == max_c joint (monotonicity)
    float sV = sig_f32_stepwise(v);
    float jv = __fsqrt_rn(sV * sc);
    if (jv == jm) {                           // possible earlier-index label tie
        int f = atomicAdd(&cnt[13], 1);
        if (f < FCAP) flags[f] = (unsigned)g;
    }
    unsigned int bits = __float_as_uint(jm);  // positive -> bit order == value order
    unsigned long long key = ((unsigned long long)bits << 32) | (0xFFFFFFFFu - (unsigned)g);
    keys[g] = key;
    labels[g] = idx;
    atomicAdd(&hist[lv * NB + (int)(bits >> 12)], 1);
}

// ---------------- kernel 1c: exact label cleanup for flagged (tied) points ----------------
__global__ void cleanup_kernel(const float* __restrict__ cls0, const float* __restrict__ cls1,
                               const float* __restrict__ cls2,
                               const float* __restrict__ ctn0, const float* __restrict__ ctn1,
                               const float* __restrict__ ctn2,
                               const int* __restrict__ cnt, const unsigned* __restrict__ flags,
                               int* __restrict__ labels) {
    int nf = cnt[13]; if (nf > FCAP) nf = FCAP;
    for (int t = threadIdx.x; t < nf; t += 256) {
        int g = (int)flags[t];
        int lv, p, HW;
        locate(g, lv, p, HW);
        const float* cls = (lv == 0) ? cls0 : ((lv == 1) ? cls1 : cls2);
        const float* ctn = (lv == 0) ? ctn0 : ((lv == 1) ? ctn1 : ctn2);
        float sc = sig_f32_stepwise(ctn[p]);
        float best = -1.0f; int lab = 0;
        for (int c = 0; c < 80; c++) {
            float s  = sig_f32_stepwise(cls[c * HW + p]);
            float sj = __fsqrt_rn(s * sc);
            if (sj > best) { best = sj; lab = c; }   // first-occurrence argmax
        }
        labels[g] = lab;
    }
}

// ---------------- kernel 2: per-level cutoff bin via suffix scan ----------------
__global__ void thresh_kernel(const int* __restrict__ hist, int* __restrict__ cnt) {
    int lv = blockIdx.x, tid = threadIdx.x;
    const int* h = hist + lv * NB;
    __shared__ int part[1024];
    __shared__ int s_chunk, s_above;
    __shared__ int bins[257];

    const int4* h4 = (const int4*)(h + tid * 256);
    int sum = 0;
#pragma unroll 16
    for (int k = 0; k < 64; k++) { int4 q = h4[k]; sum += q.x + q.y + q.z + q.w; }
    part[tid] = sum;
    __syncthreads();
    for (int off = 1; off < 1024; off <<= 1) {
        int v = part[tid] + ((tid + off < 1024) ? part[tid + off] : 0);
        __syncthreads(); part[tid] = v; __syncthreads();
    }
    int nxt = (tid < 1023) ? part[tid + 1] : 0;
    if (part[tid] >= K_TOP && nxt < K_TOP) { s_chunk = tid; s_above = nxt; }
    __syncthreads();
    int chunk = s_chunk, above = s_above;

    if (tid < 256) bins[tid] = h[chunk * 256 + tid];
    __syncthreads();
    for (int off = 1; off < 256; off <<= 1) {
        int v = 0;
        if (tid < 256) v = bins[tid] + ((tid + off < 256) ? bins[tid + off] : 0);
        __syncthreads(); if (tid < 256) bins[tid] = v; __syncthreads();
    }
    if (tid < 256) {
        int ge    = above + bins[tid];
        int genxt = above + ((tid < 255) ? bins[tid + 1] : 0);
        if (ge >= K_TOP && genxt < K_TOP) {
            cnt[6 + lv] = chunk * 256 + tid;  // cutoff bin B
            cnt[9 + lv] = K_TOP - genxt;      // R needed from bin B
        }
    }
}

// ---------------- kernel 3: compact sure / candidate keys ----------------
__global__ void compact_kernel(const unsigned long long* __restrict__ keys,
                               int* __restrict__ cnt,
                               unsigned long long* __restrict__ sure,
                               unsigned long long* __restrict__ cand) {
    int g = blockIdx.x * blockDim.x + threadIdx.x;
    if (g >= NPTS) return;
    int lv = (g < 65536) ? 0 : (g < 81920 ? 1 : 2);
    unsigned long long key = keys[g];
    int bin = (int)(key >> 44);      // == f32 bits >> 12
    int B = cnt[6 + lv];
    if (bin > B) {
        int i = atomicAdd(&cnt[0 + lv], 1);
        sure[lv * 1024 + i] = key;
    } else if (bin == B) {
        int i = atomicAdd(&cnt[3 + lv], 1);
        if (i < CAND_CAP) cand[lv * CAND_CAP + i] = key;
    }
}

// ---------------- kernel 4: per-level candidate sort + fully-sorted level list ----------------
__global__ void select_kernel(const int* __restrict__ cnt,
                              const unsigned long long* __restrict__ sure,
                              unsigned long long* __restrict__ cand,
                              unsigned long long* __restrict__ surv) {
    int lv = blockIdx.x, tid = threadIdx.x;
    unsigned long long* c = cand + lv * CAND_CAP;
    int n = cnt[3 + lv]; if (n > CAND_CAP) n = CAND_CAP;
    int R = cnt[9 + lv];
    int Ca = K_TOP - R;
    int m = 1; while (m < n) m <<= 1;
    for (int t = n + tid; t < m; t += 1024) c[t] = 0ULL;
    __syncthreads();
    for (int k = 2; k <= m; k <<= 1)
        for (int j = k >> 1; j > 0; j >>= 1) {
            for (int t = tid; t < m; t += 1024) {
                int l = t ^ j;
                if (l > t) {
                    unsigned long long a = c[t], b = c[l];
                    if (((t & k) == 0) ? (a < b) : (a > b)) { c[t] = b; c[l] = a; }
                }
            }
            __syncthreads();
        }
    // build the level's 1000-list (sure unordered + cand top-R) and sort it fully
    __shared__ unsigned long long s[1024];
    s[tid] = (tid < Ca) ? sure[lv * 1024 + tid]
                        : ((tid < K_TOP) ? c[tid - Ca] : 0ULL);
    __syncthreads();
    for (int k = 2; k <= 1024; k <<= 1)
        for (int j = k >> 1; j > 0; j >>= 1) {
            int l = tid ^ j;
            if (l > tid) {
                unsigned long long a = s[tid], b = s[l];
                if (((tid & k) == 0) ? (a < b) : (a > b)) { s[tid] = b; s[l] = a; }
            }
            __syncthreads();
        }
    if (tid < K_TOP) surv[lv * K_TOP + tid] = s[tid];    // sorted descending
}

// ---------------- kernel 5: 3-way merge by ranking + emit ----------------
__global__ __launch_bounds__(1024) void merge_emit_kernel(
        const unsigned long long* __restrict__ surv,
        const int* __restrict__ labels,
        const float* __restrict__ reg0, const float* __restrict__ reg1,
        const float* __restrict__ reg2,
        const float* __restrict__ scales,
        float* __restrict__ out) {
    __shared__ unsigned long long L[3][1024];
    __shared__ unsigned long long s[NOUT];
    int tid = threadIdx.x;
#pragma unroll
    for (int lv = 0; lv < 3; lv++)
        L[lv][tid] = (tid < K_TOP) ? surv[lv * K_TOP + tid] : 0ULL;
    __syncthreads();
    // rank = own index + count of strictly-greater keys in the other two sorted lists
    for (int e = tid; e < NOUT; e += 1024) {
        int a = e / K_TOP, i = e - a * K_TOP;
        unsigned long long key = L[a][i];
        int rank = i;
#pragma unroll
        for (int b = 0; b < 3; b++) {
            if (b == a) continue;
            int lo = 0, hi = K_TOP;
            while (lo < hi) {
                int mid = (lo + hi) >> 1;
                if (L[b][mid] > key) lo = mid + 1; else hi = mid;
            }
            rank += lo;
        }
        s[rank] = key;    // keys unique -> bijective ranking
    }
    __syncthreads();
    for (int r = tid; r < NOUT; r += 1024) {
        unsigned long long key = s[r];
        unsigned int bits = (unsigned)(key >> 32);
        float score = __uint_as_float(bits);
        unsigned int g = 0xFFFFFFFFu - (unsigned)(key & 0xFFFFFFFFULL);
        int lv, p;
        if (g < 65536u)      { lv = 0; p = (int)g; }
        else if (g < 81920u) { lv = 1; p = (int)g - 65536; }
        else                 { lv = 2; p = (int)g - 81920; }
        const float* rp = (lv == 0) ? reg0 : ((lv == 1) ? reg1 : reg2);
        int HW = (lv == 0) ? 65536 : ((lv == 1) ? 16384 : 4096);
        int W = 256 >> lv;
        float strideF = (float)(8 << lv);
        float scale = scales[lv];
        int x = p & (W - 1);
        int y = p >> (8 - lv);
        float r0 = fmaxf(0.0f, rp[0 * HW + p] * scale) * strideF;
        float r1 = fmaxf(0.0f, rp[1 * HW + p] * scale) * strideF;
        float r2 = fmaxf(0.0f, rp[2 * HW + p] * scale) * strideF;
        float r3 = fmaxf(0.0f, rp[3 * HW + p] * scale) * strideF;
        float ax = ((float)x + 0.5f) * strideF;
        float ay = ((float)y + 0.5f) * strideF;
        out[r * 4 + 0] = ax - r0;
        out[r * 4 + 1] = ay - r1;
        out[r * 4 + 2] = ax + r2;
        out[r * 4 + 3] = ay + r3;
        out[12000 + r] = score;
        out[15000 + r] = (float)labels[g];
    }
}

// ---------------- kernel 6: sparse suppression-edge extraction ----------------
__global__ void edge_kernel(const float* __restrict__ out,
                            unsigned* __restrict__ edges_g, int* __restrict__ cnt) {
    int j = blockIdx.y;
    int i = blockIdx.x * 1024 + threadIdx.x;
    if (i >= j) return;
    float x1i = out[i * 4 + 0], y1i = out[i * 4 + 1];
    float x2i = out[i * 4 + 2], y2i = out[i * 4 + 3];
    float x1j = out[j * 4 + 0], y1j = out[j * 4 + 1];
    float x2j = out[j * 4 + 2], y2j = out[j * 4 + 3];
    float ai = (x2i - x1i) * (y2i - y1i);
    float aj = (x2j - x1j) * (y2j - y1j);
    float xx1 = fmaxf(x1i, x1j), yy1 = fmaxf(y1i, y1j);
    float xx2 = fminf(x2i, x2j), yy2 = fminf(y2i, y2j);
    float ww = fmaxf(1e-10f, xx2 - xx1);
    float hh = fmaxf(1e-10f, yy2 - yy1);
    float inter = ww * hh;
    float iou = inter / (((ai + aj) - inter) + 1e-14f);
    if ((double)iou > 0.6) {
        int e = atomicAdd(&cnt[12], 1);
        if (e < ECAP) edges_g[e] = ((unsigned)i << 12) | (unsigned)j;
    }
}

// ---------------- kernel 7: sparse sequential NMS (single block) ----------------
__global__ __launch_bounds__(1024) void nms_sparse_kernel(
        const unsigned* __restrict__ edges_g,
        const int* __restrict__ cnt,
        const float* __restrict__ scores_s,
        float* __restrict__ keep_out) {
    __shared__ unsigned ed[ECAP];
    __shared__ unsigned long long supLds[NWORDS];
    int tid = threadIdx.x;
    int E = cnt[12]; if (E > ECAP) E = ECAP;
    int m = 1; while (m < E) m <<= 1;
    for (int t = tid; t < m; t += 1024) ed[t] = (t < E) ? edges_g[t] : 0xFFFFFFFFu;
    __syncthreads();
    for (int k = 2; k <= m; k <<= 1)
        for (int j = k >> 1; j > 0; j >>= 1) {
            for (int t = tid; t < m; t += 1024) {
                int l = t ^ j;
                if (l > t) {
                    unsigned a = ed[t], b = ed[l];
                    if (((t & k) == 0) ? (a > b) : (a < b)) { ed[t] = b; ed[l] = a; }
                }
            }
            __syncthreads();
        }
    if (tid < 64) {
        int lane = tid;
        unsigned long long supW = 0ULL;
        int ep = 0;
        for (int c = 0; c < NWORDS; c++) {
            unsigned long long cw = __shfl(supW, c, 64);
            int hi = (c + 1) * 64;
            while (ep < E) {
                unsigned k = ed[ep];
                int i = (int)(k >> 12);
                if (i >= hi) break;
                int j = (int)(k & 4095);
                if (!((cw >> (i & 63)) & 1ULL)) {
                    if ((j >> 6) == c) cw |= 1ULL << (j & 63);
                    else if (lane == (j >> 6)) supW |= 1ULL << (j & 63);
                }
                ep++;
            }
            if (lane == c) supW = cw;
        }
        if (lane < NWORDS) supLds[lane] = supW;
    }
    __syncthreads();
    for (int j = tid; j < NOUT; j += 1024) {
        bool s = (supLds[j >> 6] >> (j & 63)) & 1ULL;
        float scv = scores_s[j];
        keep_out[j] = (!s && ((double)scv > 0.05)) ? 1.0f : 0.0f;
    }
}

extern "C" void kernel_launch(void* const* d_in, const int* in_sizes, int n_in,
                              void* d_out, int out_size, void* d_ws, size_t ws_size,
                              hipStream_t stream) {
    const float* cls0 = (const float*)d_in[0];
    const float* reg0 = (const float*)d_in[1];
    const float* ctn0 = (const float*)d_in[2];
    const float* cls1 = (const float*)d_in[3];
    const float* reg1 = (const float*)d_in[4];
    const float* ctn1 = (const float*)d_in[5];
    const float* cls2 = (const float*)d_in[6];
    const float* reg2 = (const float*)d_in[7];
    const float* ctn2 = (const float*)d_in[8];
    const float* scales = (const float*)d_in[9];

    char* ws = (char*)d_ws;
    int* hist = (int*)(ws + HIST_OFF);
    int* cnt  = (int*)(ws + CNT_OFF);
    unsigned long long* keys = (unsigned long long*)(ws + KEYS_OFF);
    int* labels = (int*)(ws + LAB_OFF);
    unsigned long long* sure = (unsigned long long*)(ws + SURE_OFF);
    unsigned long long* cand = (unsigned long long*)(ws + CAND_OFF);
    unsigned long long* surv = (unsigned long long*)(ws + SURV_OFF);
    unsigned* edges = (unsigned*)(ws + EDGE_OFF);
    unsigned* flags = (unsigned*)(ws + FLAG_OFF);
    float* pm = (float*)(ws + PM_OFF);
    float* pv = (float*)(ws + PV_OFF);
    int* pidx = (int*)(ws + PIDX_OFF);
    float* out = (float*)d_out;

    dim3 pg((NPTS + 255) / 256, NCHUNK);
    partial_kernel<<<pg, 256, 0, stream>>>(cls0, cls1, cls2, pm, pv, pidx, hist);
    combine_kernel<<<(NPTS + 255) / 256, 256, 0, stream>>>(ctn0, ctn1, ctn2, pm, pv, pidx,
                                                           keys, labels, hist, cnt, flags);
    cleanup_kernel<<<1, 256, 0, stream>>>(cls0, cls1, cls2, ctn0, ctn1, ctn2, cnt, flags, labels);
    thresh_kernel<<<3, 1024, 0, stream>>>(hist, cnt);
    compact_kernel<<<(NPTS + 255) / 256, 256, 0, stream>>>(keys, cnt, sure, cand);
    select_kernel<<<3, 1024, 0, stream>>>(cnt, sure, cand, surv);
    merge_emit_kernel<<<1, 1024, 0, stream>>>(surv, labels, reg0, reg1, reg2, scales, out);
    dim3 eg((NOUT + 1023) / 1024, NOUT);
    edge_kernel<<<eg, 1024, 0, stream>>>(out, edges, cnt);
    nms_sparse_kernel<<<1, 1024, 0, stream>>>(edges, cnt, out + 12000, out + 18000);
}